// Round 9
// baseline (636.789 us; speedup 1.0000x reference)
//
#include <hip/hip_runtime.h>

#define NN 100000
#define NE 3200000
#define HM 30
#define HG 10
#define MAXK 26
#define OVF_CAP 8192

typedef float __attribute__((ext_vector_type(2))) f32x2;

__device__ __forceinline__ f32x2 pkfma(f32x2 a, f32x2 b, f32x2 c) {
#if __has_builtin(__builtin_elementwise_fma)
    return __builtin_elementwise_fma(a, b, c);
#else
    f32x2 r; r.x = fmaf(a.x, b.x, c.x); r.y = fmaf(a.y, b.y, c.y); return r;
#endif
}

// ---------------- Stage -1: transpose+pad weights into ws ----------------
__global__ __launch_bounds__(256) void wtrans_kernel(
    const float* __restrict__ W0, const float* __restrict__ W1,
    const float* __restrict__ W2,
    float* __restrict__ W0T, float* __restrict__ W1T, float* __restrict__ W2T)
{
    for (int idx = threadIdx.x; idx < HM * 16; idx += 256) {
        int j = idx >> 4, i = idx & 15;
        W0T[idx] = (i < 13) ? W0[i * HM + j] : 0.f;
    }
    for (int idx = threadIdx.x; idx < HM * 32; idx += 256) {
        int j = idx >> 5, i = idx & 31;
        float v1 = (i < HM) ? W1[i * HM + j] : 0.f;
        float v2 = (i < HM) ? W2[i * HM + j] : 0.f;
        W1T[idx] = v1;
        W2T[idx] = v2;
    }
}

// ---------------- Stage 0: pack node features + xw ----------------
__global__ __launch_bounds__(256) void pack_kernel(
    const float* __restrict__ x, const float* __restrict__ token,
    const float* __restrict__ Wc,
    float* __restrict__ xall8, float* __restrict__ xwp)
{
    __shared__ float sWc[6 * HG];
    if (threadIdx.x < 6 * HG) sWc[threadIdx.x] = Wc[threadIdx.x];
    __syncthreads();

    int n = blockIdx.x * 256 + threadIdx.x;
    if (n >= NN) return;

    float xa[6];
    xa[0] = x[n];
    #pragma unroll
    for (int i = 0; i < 5; i++) xa[1 + i] = token[n * 5 + i];

    float4* x4 = (float4*)xall8;
    x4[n * 2 + 0] = make_float4(xa[0], xa[1], xa[2], xa[3]);
    x4[n * 2 + 1] = make_float4(xa[4], xa[5], 0.f, 0.f);

    float w[12];
    #pragma unroll
    for (int k = 0; k < HG; k++) {
        float a = 0.f;
        #pragma unroll
        for (int i = 0; i < 6; i++) a = fmaf(xa[i], sWc[i * HG + k], a);
        w[k] = a;
    }
    w[10] = 0.f; w[11] = 0.f;
    float4* wp = (float4*)(xwp + (size_t)n * 12);
    wp[0] = make_float4(w[0], w[1], w[2], w[3]);
    wp[1] = make_float4(w[4], w[5], w[6], w[7]);
    wp[2] = make_float4(w[8], w[9], w[10], w[11]);
}

// Epilogue for one edge.
__device__ __forceinline__ void finish_edge(
    int e, int s, int t, float l0, float l1,
    const float* __restrict__ gum, const float* __restrict__ ee,
    float wl, float blv,
    float2* __restrict__ slots, int* __restrict__ cnt,
    int* __restrict__ ohead, int* __restrict__ onxt,
    float* __restrict__ ovf_w, int* __restrict__ ovf_s, int* __restrict__ novf)
{
    const float2 g2 = ((const float2*)gum)[e];
    float v0 = l0 + g2.x;
    float v1 = l1 + g2.y;

    // forward: edge_value = (v1 > v0) ? 1 : 0; active iff edge_value == 0
    float ew = 0.f;
    if (!(v1 > v0)) {
        const float2 e2 = ((const float2*)ee)[e];
        float z = fmaf(e2.x, wl, blv);
        ew = e2.y / (1.f + __expf(-z));
    }
    if (ew != 0.f) {
        int slot = atomicAdd(&cnt[t], 1);
        if (slot < MAXK) {
            slots[(size_t)t * MAXK + slot] = make_float2(ew, __int_as_float(s));
        } else {
            int i = atomicAdd(novf, 1);
            if (i < OVF_CAP) {
                ovf_w[i] = ew;
                ovf_s[i] = s;
                onxt[i] = atomicExch(&ohead[t], i);
            }
        }
    }
}

// ---------------- Stage 1: per-edge MLP, pk weights, 2 edges/thread --------
// Round-8 counters: 1-edge pk = 208us wall vs ~69us VALU -> ~67% stall on
// the serialized SGPR weight stream (32-SGPR rows, ~3 fit in budget ->
// every row's s_load wait exposed). 2 edges/thread: each weight row feeds
// TWO pk streams (half the waits per edge, 2x ILP per wait).
// amdgpu_waves_per_eu(1,4): cap occupancy target at 4 waves/SIMD (HW only
// achieves 3.4 anyway) -> per-wave VGPR budget 128, so the ~100 live floats
// fit in ARCH VGPRs (round-4's churn at VGPR=68 was the allocator targeting
// 8 waves).
__global__ __launch_bounds__(256)
__attribute__((amdgpu_waves_per_eu(1, 4)))
void edge_mlp8_kernel(
    const float* __restrict__ xall8,
    const float* __restrict__ eg, const float* __restrict__ ee,
    const float* __restrict__ gum, const int* __restrict__ eidx,
    const float* __restrict__ W0T, const float* __restrict__ b0,
    const float* __restrict__ W1T, const float* __restrict__ b1,
    const float* __restrict__ W2T, const float* __restrict__ b2,
    const float* __restrict__ W3, const float* __restrict__ b3,
    const float* __restrict__ Wl, const float* __restrict__ bl,
    float2* __restrict__ slots, int* __restrict__ cnt,
    int* __restrict__ ohead, int* __restrict__ onxt,
    float* __restrict__ ovf_w, int* __restrict__ ovf_s, int* __restrict__ novf)
{
    int base = blockIdx.x * 512;                 // NE == 6250*512 exactly
    int eA = base + threadIdx.x;
    int eB = base + 256 + threadIdx.x;

    int sA = eidx[eA];
    int tA = eidx[NE + eA];
    int sB = eidx[eB];
    int tB = eidx[NE + eB];

    const float4* x4 = (const float4*)xall8;
    f32x2 efA[7], efB[7];
    {
        float4 qa = x4[sA * 2], qb = x4[sA * 2 + 1];
        float4 qc = x4[tA * 2], qd = x4[tA * 2 + 1];
        efA[0] = f32x2{ qa.x, qa.y };
        efA[1] = f32x2{ qa.z, qa.w };
        efA[2] = f32x2{ qb.x, qb.y };
        efA[3] = f32x2{ qc.x, qc.y };
        efA[4] = f32x2{ qc.z, qc.w };
        efA[5] = f32x2{ qd.x, qd.y };
        efA[6] = f32x2{ eg[eA], 0.f };
    }
    {
        float4 qa = x4[sB * 2], qb = x4[sB * 2 + 1];
        float4 qc = x4[tB * 2], qd = x4[tB * 2 + 1];
        efB[0] = f32x2{ qa.x, qa.y };
        efB[1] = f32x2{ qa.z, qa.w };
        efB[2] = f32x2{ qb.x, qb.y };
        efB[3] = f32x2{ qc.x, qc.y };
        efB[4] = f32x2{ qc.z, qc.w };
        efB[5] = f32x2{ qd.x, qd.y };
        efB[6] = f32x2{ eg[eB], 0.f };
    }

    float hA[HM], hB[HM];

    #pragma unroll
    for (int j = 0; j < HM; j++) {
        const f32x2* w2 = (const f32x2*)(W0T + j * 16);
        f32x2 aA = f32x2{ b0[j], 0.f };
        f32x2 aB = aA;
        #pragma unroll
        for (int p = 0; p < 7; p++) {
            f32x2 w = w2[p];
            aA = pkfma(efA[p], w, aA);
            aB = pkfma(efB[p], w, aB);
        }
        hA[j] = fmaxf(aA.x + aA.y, 0.f);
        hB[j] = fmaxf(aB.x + aB.y, 0.f);
    }

    float gA[HM], gB[HM];
    {
        f32x2 hpA[15], hpB[15];
        #pragma unroll
        for (int p = 0; p < 15; p++) {
            hpA[p] = f32x2{ hA[2 * p], hA[2 * p + 1] };
            hpB[p] = f32x2{ hB[2 * p], hB[2 * p + 1] };
        }
        #pragma unroll
        for (int j = 0; j < HM; j++) {
            const f32x2* w2 = (const f32x2*)(W1T + j * 32);
            f32x2 aA = f32x2{ b1[j], 0.f };
            f32x2 aB = aA;
            #pragma unroll
            for (int p = 0; p < 15; p++) {
                f32x2 w = w2[p];
                aA = pkfma(hpA[p], w, aA);
                aB = pkfma(hpB[p], w, aB);
            }
            gA[j] = fmaxf(aA.x + aA.y, 0.f);
            gB[j] = fmaxf(aB.x + aB.y, 0.f);
        }
    }
    {
        f32x2 gpA[15], gpB[15];
        #pragma unroll
        for (int p = 0; p < 15; p++) {
            gpA[p] = f32x2{ gA[2 * p], gA[2 * p + 1] };
            gpB[p] = f32x2{ gB[2 * p], gB[2 * p + 1] };
        }
        #pragma unroll
        for (int j = 0; j < HM; j++) {
            const f32x2* w2 = (const f32x2*)(W2T + j * 32);
            f32x2 aA = f32x2{ b2[j], 0.f };
            f32x2 aB = aA;
            #pragma unroll
            for (int p = 0; p < 15; p++) {
                f32x2 w = w2[p];
                aA = pkfma(gpA[p], w, aA);
                aB = pkfma(gpB[p], w, aB);
            }
            hA[j] = fmaxf(aA.x + aA.y, 0.f);
            hB[j] = fmaxf(aB.x + aB.y, 0.f);
        }
    }

    float l0A = b3[0], l1A = b3[1];
    float l0B = l0A, l1B = l1A;
    #pragma unroll
    for (int i = 0; i < HM; i++) {
        float w0 = W3[i * 2 + 0];
        float w1 = W3[i * 2 + 1];
        l0A = fmaf(hA[i], w0, l0A);
        l1A = fmaf(hA[i], w1, l1A);
        l0B = fmaf(hB[i], w0, l0B);
        l1B = fmaf(hB[i], w1, l1B);
    }

    float wl = Wl[0], blv = bl[0];
    finish_edge(eA, sA, tA, l0A, l1A, gum, ee, wl, blv,
                slots, cnt, ohead, onxt, ovf_w, ovf_s, novf);
    finish_edge(eB, sB, tB, l0B, l1B, gum, ee, wl, blv,
                slots, cnt, ohead, onxt, ovf_w, ovf_s, novf);
}

// ---------------- Stage 2: per-node deg -> dis; scale xwp in place to z ----
__global__ __launch_bounds__(256) void node_deg_kernel(
    const float2* __restrict__ slots, const int* __restrict__ cnt,
    const int* __restrict__ ohead, const int* __restrict__ onxt,
    const float* __restrict__ ovf_w,
    float* __restrict__ xwp, float* __restrict__ dis)
{
    int n = blockIdx.x * 256 + threadIdx.x;
    if (n >= NN) return;

    int c = cnt[n];
    int cc = c < MAXK ? c : MAXK;
    float deg = 0.f;
    for (int j = 0; j < cc; j++) deg += slots[(size_t)n * MAXK + j].x;
    for (int i = ohead[n]; i >= 0; i = onxt[i]) deg += ovf_w[i];

    float d = rsqrtf(deg + 1.0f);   // +1 = self loop
    dis[n] = d;

    float4* wp = (float4*)(xwp + (size_t)n * 12);
    #pragma unroll
    for (int q = 0; q < 3; q++) {
        float4 v = wp[q];
        v.x *= d; v.y *= d; v.z *= d; v.w *= d;
        wp[q] = v;
    }
}

// ---------------- Stage 3: gather, 8 lanes per node, pre-scaled z ----------
// Round-8: tail flat at ~165us regardless of z pre-scaling -> gather is
// TLP/latency-bound on the dependent slot->z chains. 8 lanes/node doubles
// resident parallelism (800k threads); 3-round shfl_xor reduction.
__global__ __launch_bounds__(256) void gather_out5_kernel(
    const float2* __restrict__ slots, const int* __restrict__ cnt,
    const int* __restrict__ ohead, const int* __restrict__ onxt,
    const float* __restrict__ ovf_w, const int* __restrict__ ovf_s,
    const float* __restrict__ z, const float* __restrict__ dis,
    const float* __restrict__ bc, const float* __restrict__ Wo,
    const float* __restrict__ bo, float* __restrict__ out)
{
    __shared__ float sbc[12], sWo[12], sbo;
    if (threadIdx.x < 12) {
        sbc[threadIdx.x] = (threadIdx.x < HG) ? bc[threadIdx.x] : 0.f;
        sWo[threadIdx.x] = (threadIdx.x < HG) ? Wo[threadIdx.x] : 0.f;
    }
    if (threadIdx.x == 0) sbo = bo[0];
    __syncthreads();

    int tg = blockIdx.x * 256 + threadIdx.x;
    int n = tg >> 3;
    int k = tg & 7;
    if (n >= NN) return;

    const float4* Z = (const float4*)z;
    float4 A0 = make_float4(0.f, 0.f, 0.f, 0.f), A1 = A0, A2 = A0;

    int c = cnt[n];
    int cc = c < MAXK ? c : MAXK;
    for (int j = k; j < cc; j += 8) {
        float2 p = slots[(size_t)n * MAXK + j];
        float w = p.x;
        int s = __float_as_int(p.y);
        float4 z0 = Z[s * 3], z1 = Z[s * 3 + 1], z2 = Z[s * 3 + 2];
        A0.x = fmaf(w, z0.x, A0.x); A0.y = fmaf(w, z0.y, A0.y);
        A0.z = fmaf(w, z0.z, A0.z); A0.w = fmaf(w, z0.w, A0.w);
        A1.x = fmaf(w, z1.x, A1.x); A1.y = fmaf(w, z1.y, A1.y);
        A1.z = fmaf(w, z1.z, A1.z); A1.w = fmaf(w, z1.w, A1.w);
        A2.x = fmaf(w, z2.x, A2.x); A2.y = fmaf(w, z2.y, A2.y);
    }
    if (k == 0) {
        for (int i = ohead[n]; i >= 0; i = onxt[i]) {
            float w = ovf_w[i];
            int s = ovf_s[i];
            float4 z0 = Z[s * 3], z1 = Z[s * 3 + 1], z2 = Z[s * 3 + 2];
            A0.x = fmaf(w, z0.x, A0.x); A0.y = fmaf(w, z0.y, A0.y);
            A0.z = fmaf(w, z0.z, A0.z); A0.w = fmaf(w, z0.w, A0.w);
            A1.x = fmaf(w, z1.x, A1.x); A1.y = fmaf(w, z1.y, A1.y);
            A1.z = fmaf(w, z1.z, A1.z); A1.w = fmaf(w, z1.w, A1.w);
            A2.x = fmaf(w, z2.x, A2.x); A2.y = fmaf(w, z2.y, A2.y);
        }
        // self loop: + z[n] (w=1)
        float4 s0 = Z[n * 3], s1 = Z[n * 3 + 1], s2 = Z[n * 3 + 2];
        A0.x += s0.x; A0.y += s0.y; A0.z += s0.z; A0.w += s0.w;
        A1.x += s1.x; A1.y += s1.y; A1.z += s1.z; A1.w += s1.w;
        A2.x += s2.x; A2.y += s2.y;
    }

    float v[10] = { A0.x, A0.y, A0.z, A0.w, A1.x, A1.y, A1.z, A1.w, A2.x, A2.y };
    #pragma unroll
    for (int q = 0; q < 10; q++) {
        v[q] += __shfl_xor(v[q], 1);
        v[q] += __shfl_xor(v[q], 2);
        v[q] += __shfl_xor(v[q], 4);
    }

    if (k == 0) {
        float d = dis[n];
        float o = sbo;
        #pragma unroll
        for (int q = 0; q < HG; q++)
            o = fmaf(fmaf(v[q], d, sbc[q]), sWo[q], o);
        out[n] = 1.f / (1.f + __expf(-o));
    }
}

// ================= Fallback path (Round-1 scatter) =================
__global__ __launch_bounds__(256) void edge_mlp_kernel(
    const float* __restrict__ x, const float* __restrict__ token,
    const float* __restrict__ eg, const float* __restrict__ ee,
    const float* __restrict__ gum, const int* __restrict__ eidx,
    const float* __restrict__ W0, const float* __restrict__ b0,
    const float* __restrict__ W1, const float* __restrict__ b1,
    const float* __restrict__ W2, const float* __restrict__ b2,
    const float* __restrict__ W3, const float* __restrict__ b3,
    const float* __restrict__ Wl, const float* __restrict__ bl,
    float* __restrict__ ew_out, float* __restrict__ deg)
{
    __shared__ float sW0[13 * HM];
    __shared__ float sW1[HM * HM];
    __shared__ float sW2[HM * HM];
    __shared__ float sW3f[HM * 2];
    __shared__ float sb0[HM], sb1[HM], sb2[HM], sb3[2];
    __shared__ float sWl, sbl;

    for (int i = threadIdx.x; i < 13 * HM; i += 256) sW0[i] = W0[i];
    for (int i = threadIdx.x; i < HM * HM; i += 256) sW1[i] = W1[i];
    for (int i = threadIdx.x; i < HM * HM; i += 256) sW2[i] = W2[i];
    for (int i = threadIdx.x; i < HM * 2; i += 256) sW3f[i] = W3[i];
    if (threadIdx.x < HM) {
        sb0[threadIdx.x] = b0[threadIdx.x];
        sb1[threadIdx.x] = b1[threadIdx.x];
        sb2[threadIdx.x] = b2[threadIdx.x];
    }
    if (threadIdx.x < 2) sb3[threadIdx.x] = b3[threadIdx.x];
    if (threadIdx.x == 0) { sWl = Wl[0]; sbl = bl[0]; }
    __syncthreads();

    int e = blockIdx.x * 256 + threadIdx.x;
    if (e >= NE) return;
    int s = eidx[e];
    int t = eidx[NE + e];

    float ef[13];
    ef[0] = x[s];
    #pragma unroll
    for (int i = 0; i < 5; i++) ef[1 + i] = token[s * 5 + i];
    ef[6] = x[t];
    #pragma unroll
    for (int i = 0; i < 5; i++) ef[7 + i] = token[t * 5 + i];
    ef[12] = eg[e];

    float h[HM], h2[HM];
    #pragma unroll
    for (int j = 0; j < HM; j++) {
        float a = sb0[j];
        #pragma unroll
        for (int i = 0; i < 13; i++) a = fmaf(ef[i], sW0[i * HM + j], a);
        h[j] = a > 0.f ? a : 0.f;
    }
    #pragma unroll
    for (int j = 0; j < HM; j++) {
        float a = sb1[j];
        #pragma unroll
        for (int i = 0; i < HM; i++) a = fmaf(h[i], sW1[i * HM + j], a);
        h2[j] = a > 0.f ? a : 0.f;
    }
    #pragma unroll
    for (int j = 0; j < HM; j++) {
        float a = sb2[j];
        #pragma unroll
        for (int i = 0; i < HM; i++) a = fmaf(h2[i], sW2[i * HM + j], a);
        h[j] = a > 0.f ? a : 0.f;
    }
    float l0 = sb3[0], l1 = sb3[1];
    #pragma unroll
    for (int i = 0; i < HM; i++) {
        l0 = fmaf(h[i], sW3f[i * 2 + 0], l0);
        l1 = fmaf(h[i], sW3f[i * 2 + 1], l1);
    }
    const float2 g2 = ((const float2*)gum)[e];
    float v0 = l0 + g2.x, v1 = l1 + g2.y;
    float ew = 0.f;
    if (!(v1 > v0)) {
        const float2 ee2 = ((const float2*)ee)[e];
        float z = fmaf(ee2.x, sWl, sbl);
        ew = ee2.y / (1.f + __expf(-z));
    }
    ew_out[e] = ew;
    if (ew != 0.f) atomicAdd(&deg[t], ew);
}

__global__ __launch_bounds__(256) void node_pre_kernel(
    const float* __restrict__ x, const float* __restrict__ token,
    const float* __restrict__ Wc, const float* __restrict__ deg,
    float* __restrict__ xw, float* __restrict__ dis)
{
    __shared__ float sWc[6 * HG];
    if (threadIdx.x < 6 * HG) sWc[threadIdx.x] = Wc[threadIdx.x];
    __syncthreads();
    int n = blockIdx.x * 256 + threadIdx.x;
    if (n >= NN) return;
    float xa[6];
    xa[0] = x[n];
    #pragma unroll
    for (int i = 0; i < 5; i++) xa[1 + i] = token[n * 5 + i];
    #pragma unroll
    for (int k = 0; k < HG; k++) {
        float a = 0.f;
        #pragma unroll
        for (int i = 0; i < 6; i++) a = fmaf(xa[i], sWc[i * HG + k], a);
        xw[n * HG + k] = a;
    }
    dis[n] = rsqrtf(deg[n] + 1.0f);
}

__global__ __launch_bounds__(256) void edge_scatter_kernel(
    const int* __restrict__ eidx, const float* __restrict__ ew,
    const float* __restrict__ dis, const float* __restrict__ xw,
    float* __restrict__ agg)
{
    int e = blockIdx.x * 256 + threadIdx.x;
    if (e >= NE) return;
    float w = ew[e];
    if (w == 0.f) return;
    int s = eidx[e];
    int t = eidx[NE + e];
    float norm = dis[s] * w * dis[t];
    #pragma unroll
    for (int k = 0; k < HG; k++)
        atomicAdd(&agg[t * HG + k], norm * xw[s * HG + k]);
}

__global__ __launch_bounds__(256) void node_out_kernel(
    const float* __restrict__ agg, const float* __restrict__ xw,
    const float* __restrict__ dis, const float* __restrict__ bc,
    const float* __restrict__ Wo, const float* __restrict__ bo,
    float* __restrict__ out)
{
    __shared__ float sbc[HG], sWo[HG], sbo;
    if (threadIdx.x < HG) { sbc[threadIdx.x] = bc[threadIdx.x]; sWo[threadIdx.x] = Wo[threadIdx.x]; }
    if (threadIdx.x == 0) sbo = bo[0];
    __syncthreads();
    int n = blockIdx.x * 256 + threadIdx.x;
    if (n >= NN) return;
    float d = dis[n];
    float self = d * d;
    float acc = sbo;
    #pragma unroll
    for (int k = 0; k < HG; k++) {
        float v = agg[n * HG + k] + xw[n * HG + k] * self + sbc[k];
        acc = fmaf(v, sWo[k], acc);
    }
    out[n] = 1.f / (1.f + __expf(-acc));
}

extern "C" void kernel_launch(void* const* d_in, const int* in_sizes, int n_in,
                              void* d_out, int out_size, void* d_ws, size_t ws_size,
                              hipStream_t stream) {
    const float* x   = (const float*)d_in[0];
    const float* tok = (const float*)d_in[1];
    const float* eg  = (const float*)d_in[2];
    const float* ee  = (const float*)d_in[3];
    const float* gum = (const float*)d_in[4];
    const int*   ei  = (const int*)d_in[5];
    const float* W0  = (const float*)d_in[6];
    const float* b0  = (const float*)d_in[7];
    const float* W1  = (const float*)d_in[8];
    const float* b1  = (const float*)d_in[9];
    const float* W2  = (const float*)d_in[10];
    const float* b2  = (const float*)d_in[11];
    const float* W3  = (const float*)d_in[12];
    const float* b3  = (const float*)d_in[13];
    const float* Wl  = (const float*)d_in[14];
    const float* bl  = (const float*)d_in[15];
    const float* Wc  = (const float*)d_in[16];
    const float* bc  = (const float*)d_in[17];
    const float* Wo  = (const float*)d_in[18];
    const float* bo  = (const float*)d_in[19];
    float* out = (float*)d_out;

    dim3 blk(256);
    dim3 egrid2(NE / 512);              // exact: 6250 (2 edges/thread)
    dim3 egrid(NE / 256);               // exact: 12500 (fallback)
    dim3 ngrid((NN + 255) / 256);
    dim3 g8grid((NN * 8 + 255) / 256);  // 8 lanes per node

    // New-path ws layout (float offsets)
    size_t off_xall8 = 0;                              // NN*8
    size_t off_xwp   = off_xall8 + (size_t)NN * 8;     // NN*12
    size_t off_slots = off_xwp + (size_t)NN * 12;      // NN*MAXK*2
    size_t off_cnt   = off_slots + (size_t)NN * MAXK * 2; // NN int
    size_t off_novf  = off_cnt + NN;                   // 1 int
    size_t off_dis   = off_novf + 1;                   // NN
    size_t off_ohead = off_dis + NN;                   // NN int
    size_t off_ovfw  = off_ohead + NN;                 // OVF_CAP
    size_t off_ovfs  = off_ovfw + OVF_CAP;             // OVF_CAP int
    size_t off_onxt  = off_ovfs + OVF_CAP;             // OVF_CAP int
    size_t off_w0t   = (off_onxt + OVF_CAP + 15) & ~(size_t)15; // 30*16
    size_t off_w1t   = off_w0t + 30 * 16;              // 30*32
    size_t off_w2t   = off_w1t + 30 * 32;              // 30*32
    size_t need_new  = (off_w2t + 30 * 32) * sizeof(float);

    if (ws_size >= need_new) {
        float*  ws    = (float*)d_ws;
        float*  xall8 = ws + off_xall8;
        float*  xwp   = ws + off_xwp;
        float2* slots = (float2*)(ws + off_slots);
        int*    cnt   = (int*)(ws + off_cnt);
        int*    novf  = (int*)(ws + off_novf);
        float*  dis   = ws + off_dis;
        int*    ohead = (int*)(ws + off_ohead);
        float*  ovf_w = ws + off_ovfw;
        int*    ovf_s = (int*)(ws + off_ovfs);
        int*    onxt  = (int*)(ws + off_onxt);
        float*  W0T   = ws + off_w0t;
        float*  W1T   = ws + off_w1t;
        float*  W2T   = ws + off_w2t;

        hipMemsetAsync(cnt, 0, (size_t)(NN + 1) * sizeof(int), stream);   // cnt + novf
        hipMemsetAsync(ohead, 0xFF, (size_t)NN * sizeof(int), stream);    // ohead = -1

        wtrans_kernel<<<dim3(1), blk, 0, stream>>>(W0, W1, W2, W0T, W1T, W2T);
        pack_kernel<<<ngrid, blk, 0, stream>>>(x, tok, Wc, xall8, xwp);
        edge_mlp8_kernel<<<egrid2, blk, 0, stream>>>(xall8, eg, ee, gum, ei,
                                                     W0T, b0, W1T, b1, W2T, b2,
                                                     W3, b3, Wl, bl, slots, cnt,
                                                     ohead, onxt, ovf_w, ovf_s, novf);
        node_deg_kernel<<<ngrid, blk, 0, stream>>>(slots, cnt, ohead, onxt, ovf_w,
                                                   xwp, dis);
        gather_out5_kernel<<<g8grid, blk, 0, stream>>>(slots, cnt, ohead, onxt,
                                                       ovf_w, ovf_s, xwp, dis,
                                                       bc, Wo, bo, out);
    } else {
        // Fallback: Round-1 scatter layout: [ew: NE][deg: NN][agg: NN*HG][xw: NN*HG][dis: NN]
        float* ws  = (float*)d_ws;
        float* ew  = ws;
        float* deg = ew + NE;
        float* agg = deg + NN;
        float* xw  = agg + (size_t)NN * HG;
        float* dis = xw + (size_t)NN * HG;

        hipMemsetAsync(deg, 0, (size_t)(NN + (size_t)NN * HG) * sizeof(float), stream);
        edge_mlp_kernel<<<egrid, blk, 0, stream>>>(x, tok, eg, ee, gum, ei,
                                                   W0, b0, W1, b1, W2, b2, W3, b3,
                                                   Wl, bl, ew, deg);
        node_pre_kernel<<<ngrid, blk, 0, stream>>>(x, tok, Wc, deg, xw, dis);
        edge_scatter_kernel<<<egrid, blk, 0, stream>>>(ei, ew, dis, xw, agg);
        node_out_kernel<<<ngrid, blk, 0, stream>>>(agg, xw, dis, bc, Wo, bo, out);
    }
}

// Round 10
// 384.554 us; speedup vs baseline: 1.6559x; 1.6559x over previous
//
#include <hip/hip_runtime.h>

#define NN 100000
#define NE 3200000
#define HM 30
#define HG 10
#define MAXK 26
#define OVF_CAP 8192

typedef float __attribute__((ext_vector_type(2))) f32x2;

__device__ __forceinline__ f32x2 pkfma(f32x2 a, f32x2 b, f32x2 c) {
#if __has_builtin(__builtin_elementwise_fma)
    return __builtin_elementwise_fma(a, b, c);
#else
    f32x2 r; r.x = fmaf(a.x, b.x, c.x); r.y = fmaf(a.y, b.y, c.y); return r;
#endif
}

// ---------------- Stage -1: transpose+pad weights into ws ----------------
__global__ __launch_bounds__(256) void wtrans_kernel(
    const float* __restrict__ W0, const float* __restrict__ W1,
    const float* __restrict__ W2,
    float* __restrict__ W0T, float* __restrict__ W1T, float* __restrict__ W2T)
{
    for (int idx = threadIdx.x; idx < HM * 16; idx += 256) {
        int j = idx >> 4, i = idx & 15;
        W0T[idx] = (i < 13) ? W0[i * HM + j] : 0.f;
    }
    for (int idx = threadIdx.x; idx < HM * 32; idx += 256) {
        int j = idx >> 5, i = idx & 31;
        float v1 = (i < HM) ? W1[i * HM + j] : 0.f;
        float v2 = (i < HM) ? W2[i * HM + j] : 0.f;
        W1T[idx] = v1;
        W2T[idx] = v2;
    }
}

// ---------------- Stage 0: pack node features + xw ----------------
__global__ __launch_bounds__(256) void pack_kernel(
    const float* __restrict__ x, const float* __restrict__ token,
    const float* __restrict__ Wc,
    float* __restrict__ xall8, float* __restrict__ xwp)
{
    __shared__ float sWc[6 * HG];
    if (threadIdx.x < 6 * HG) sWc[threadIdx.x] = Wc[threadIdx.x];
    __syncthreads();

    int n = blockIdx.x * 256 + threadIdx.x;
    if (n >= NN) return;

    float xa[6];
    xa[0] = x[n];
    #pragma unroll
    for (int i = 0; i < 5; i++) xa[1 + i] = token[n * 5 + i];

    float4* x4 = (float4*)xall8;
    x4[n * 2 + 0] = make_float4(xa[0], xa[1], xa[2], xa[3]);
    x4[n * 2 + 1] = make_float4(xa[4], xa[5], 0.f, 0.f);

    float w[12];
    #pragma unroll
    for (int k = 0; k < HG; k++) {
        float a = 0.f;
        #pragma unroll
        for (int i = 0; i < 6; i++) a = fmaf(xa[i], sWc[i * HG + k], a);
        w[k] = a;
    }
    w[10] = 0.f; w[11] = 0.f;
    float4* wp = (float4*)(xwp + (size_t)n * 12);
    wp[0] = make_float4(w[0], w[1], w[2], w[3]);
    wp[1] = make_float4(w[4], w[5], w[6], w[7]);
    wp[2] = make_float4(w[8], w[9], w[10], w[11]);
}

// ---------------- Stage 1: per-edge MLP, dual-pipe weight delivery --------
// Rounds 3 vs 8 differential: the ~139us edge stall is invariant to the FMA
// stream -- it is the WEIGHT-DELIVERY path. SMEM-only: ~76cy exposed wait
// per row (only ~3 rows fit the ~102-SGPR budget). LDS-only (round 0):
// broadcast pays the full return bus (~190us). Different pipes -> split
// each row: first 8 float2 pairs from SMEM, last 7 pairs from LDS (4.8KB).
// Both pipes run concurrently; per-row SGPR footprint halves so more rows
// prefetch. 1 edge/thread (2-edge forms churn: rounds 1/4/9, VGPR>90 law).
__global__ __launch_bounds__(256) void edge_mlp9_kernel(
    const float* __restrict__ xall8,
    const float* __restrict__ eg, const float* __restrict__ ee,
    const float* __restrict__ gum, const int* __restrict__ eidx,
    const float* __restrict__ W0T, const float* __restrict__ b0,
    const float* __restrict__ W1T, const float* __restrict__ b1,
    const float* __restrict__ W2T, const float* __restrict__ b2,
    const float* __restrict__ W3, const float* __restrict__ b3,
    const float* __restrict__ Wl, const float* __restrict__ bl,
    float2* __restrict__ slots, int* __restrict__ cnt,
    int* __restrict__ ohead, int* __restrict__ onxt,
    float* __restrict__ ovf_w, int* __restrict__ ovf_s, int* __restrict__ novf)
{
    __shared__ float sW0h[HM * 8];    // W0T cols 8..15  (pairs 4..6 valid)
    __shared__ float sW1h[HM * 16];   // W1T cols 16..31 (pairs 8..14 valid)
    __shared__ float sW2h[HM * 16];   // W2T cols 16..31

    for (int idx = threadIdx.x; idx < HM * 8; idx += 256)
        sW0h[idx] = W0T[(idx >> 3) * 16 + 8 + (idx & 7)];
    for (int idx = threadIdx.x; idx < HM * 16; idx += 256) {
        int j = idx >> 4, i = idx & 15;
        sW1h[idx] = W1T[j * 32 + 16 + i];
        sW2h[idx] = W2T[j * 32 + 16 + i];
    }
    __syncthreads();

    int e = blockIdx.x * 256 + threadIdx.x;   // NE == 12500*256 exactly
    int s = eidx[e];
    int t = eidx[NE + e];

    const float4* x4 = (const float4*)xall8;
    float4 qa = x4[s * 2], qb = x4[s * 2 + 1];
    float4 qc = x4[t * 2], qd = x4[t * 2 + 1];

    f32x2 ef2[7];
    ef2[0] = f32x2{ qa.x, qa.y };
    ef2[1] = f32x2{ qa.z, qa.w };
    ef2[2] = f32x2{ qb.x, qb.y };
    ef2[3] = f32x2{ qc.x, qc.y };
    ef2[4] = f32x2{ qc.z, qc.w };
    ef2[5] = f32x2{ qd.x, qd.y };
    ef2[6] = f32x2{ eg[e], 0.f };

    float h[HM], g[HM];

    #pragma unroll
    for (int j = 0; j < HM; j++) {
        const f32x2* wlo = (const f32x2*)(W0T + j * 16);   // pairs 0..3 SMEM
        const f32x2* whi = (const f32x2*)(sW0h + j * 8);   // pairs 4..6 LDS
        f32x2 a2 = f32x2{ b0[j], 0.f };
        #pragma unroll
        for (int p = 0; p < 4; p++) a2 = pkfma(ef2[p], wlo[p], a2);
        #pragma unroll
        for (int p = 0; p < 3; p++) a2 = pkfma(ef2[4 + p], whi[p], a2);
        h[j] = fmaxf(a2.x + a2.y, 0.f);
    }

    {
        f32x2 hp[15];
        #pragma unroll
        for (int p = 0; p < 15; p++) hp[p] = f32x2{ h[2 * p], h[2 * p + 1] };
        #pragma unroll
        for (int j = 0; j < HM; j++) {
            const f32x2* wlo = (const f32x2*)(W1T + j * 32);   // pairs 0..7 SMEM
            const f32x2* whi = (const f32x2*)(sW1h + j * 16);  // pairs 8..14 LDS
            f32x2 a2 = f32x2{ b1[j], 0.f };
            #pragma unroll
            for (int p = 0; p < 8; p++) a2 = pkfma(hp[p], wlo[p], a2);
            #pragma unroll
            for (int p = 0; p < 7; p++) a2 = pkfma(hp[8 + p], whi[p], a2);
            g[j] = fmaxf(a2.x + a2.y, 0.f);
        }
    }
    {
        f32x2 gp[15];
        #pragma unroll
        for (int p = 0; p < 15; p++) gp[p] = f32x2{ g[2 * p], g[2 * p + 1] };
        #pragma unroll
        for (int j = 0; j < HM; j++) {
            const f32x2* wlo = (const f32x2*)(W2T + j * 32);
            const f32x2* whi = (const f32x2*)(sW2h + j * 16);
            f32x2 a2 = f32x2{ b2[j], 0.f };
            #pragma unroll
            for (int p = 0; p < 8; p++) a2 = pkfma(gp[p], wlo[p], a2);
            #pragma unroll
            for (int p = 0; p < 7; p++) a2 = pkfma(gp[8 + p], whi[p], a2);
            h[j] = fmaxf(a2.x + a2.y, 0.f);
        }
    }

    float l0 = b3[0], l1 = b3[1];
    #pragma unroll
    for (int i = 0; i < HM; i++) {
        l0 = fmaf(h[i], W3[i * 2 + 0], l0);
        l1 = fmaf(h[i], W3[i * 2 + 1], l1);
    }

    const float2 g2 = ((const float2*)gum)[e];
    float v0 = l0 + g2.x;
    float v1 = l1 + g2.y;

    // forward: edge_value = (v1 > v0) ? 1 : 0; active iff edge_value == 0
    float ew = 0.f;
    if (!(v1 > v0)) {
        const float2 e2 = ((const float2*)ee)[e];
        float z = fmaf(e2.x, Wl[0], bl[0]);
        ew = e2.y / (1.f + __expf(-z));
    }
    if (ew != 0.f) {
        int slot = atomicAdd(&cnt[t], 1);
        if (slot < MAXK) {
            slots[(size_t)t * MAXK + slot] = make_float2(ew, __int_as_float(s));
        } else {
            int i = atomicAdd(novf, 1);
            if (i < OVF_CAP) {
                ovf_w[i] = ew;
                ovf_s[i] = s;
                onxt[i] = atomicExch(&ohead[t], i);
            }
        }
    }
}

// ---------------- Stage 2: per-node deg -> dis; scale xwp in place to z ----
__global__ __launch_bounds__(256) void node_deg_kernel(
    const float2* __restrict__ slots, const int* __restrict__ cnt,
    const int* __restrict__ ohead, const int* __restrict__ onxt,
    const float* __restrict__ ovf_w,
    float* __restrict__ xwp, float* __restrict__ dis)
{
    int n = blockIdx.x * 256 + threadIdx.x;
    if (n >= NN) return;

    int c = cnt[n];
    int cc = c < MAXK ? c : MAXK;
    float deg = 0.f;
    for (int j = 0; j < cc; j++) deg += slots[(size_t)n * MAXK + j].x;
    for (int i = ohead[n]; i >= 0; i = onxt[i]) deg += ovf_w[i];

    float d = rsqrtf(deg + 1.0f);   // +1 = self loop
    dis[n] = d;

    float4* wp = (float4*)(xwp + (size_t)n * 12);
    #pragma unroll
    for (int q = 0; q < 3; q++) {
        float4 v = wp[q];
        v.x *= d; v.y *= d; v.z *= d; v.w *= d;
        wp[q] = v;
    }
}

// ---------------- Stage 3: gather, 8 lanes per node, pre-scaled z ----------
// Round-9 tail differential: 8-lane gather = 154us tail vs 167 with 4-lane.
__global__ __launch_bounds__(256) void gather_out5_kernel(
    const float2* __restrict__ slots, const int* __restrict__ cnt,
    const int* __restrict__ ohead, const int* __restrict__ onxt,
    const float* __restrict__ ovf_w, const int* __restrict__ ovf_s,
    const float* __restrict__ z, const float* __restrict__ dis,
    const float* __restrict__ bc, const float* __restrict__ Wo,
    const float* __restrict__ bo, float* __restrict__ out)
{
    __shared__ float sbc[12], sWo[12], sbo;
    if (threadIdx.x < 12) {
        sbc[threadIdx.x] = (threadIdx.x < HG) ? bc[threadIdx.x] : 0.f;
        sWo[threadIdx.x] = (threadIdx.x < HG) ? Wo[threadIdx.x] : 0.f;
    }
    if (threadIdx.x == 0) sbo = bo[0];
    __syncthreads();

    int tg = blockIdx.x * 256 + threadIdx.x;
    int n = tg >> 3;
    int k = tg & 7;
    if (n >= NN) return;

    const float4* Z = (const float4*)z;
    float4 A0 = make_float4(0.f, 0.f, 0.f, 0.f), A1 = A0, A2 = A0;

    int c = cnt[n];
    int cc = c < MAXK ? c : MAXK;
    for (int j = k; j < cc; j += 8) {
        float2 p = slots[(size_t)n * MAXK + j];
        float w = p.x;
        int s = __float_as_int(p.y);
        float4 z0 = Z[s * 3], z1 = Z[s * 3 + 1], z2 = Z[s * 3 + 2];
        A0.x = fmaf(w, z0.x, A0.x); A0.y = fmaf(w, z0.y, A0.y);
        A0.z = fmaf(w, z0.z, A0.z); A0.w = fmaf(w, z0.w, A0.w);
        A1.x = fmaf(w, z1.x, A1.x); A1.y = fmaf(w, z1.y, A1.y);
        A1.z = fmaf(w, z1.z, A1.z); A1.w = fmaf(w, z1.w, A1.w);
        A2.x = fmaf(w, z2.x, A2.x); A2.y = fmaf(w, z2.y, A2.y);
    }
    if (k == 0) {
        for (int i = ohead[n]; i >= 0; i = onxt[i]) {
            float w = ovf_w[i];
            int s = ovf_s[i];
            float4 z0 = Z[s * 3], z1 = Z[s * 3 + 1], z2 = Z[s * 3 + 2];
            A0.x = fmaf(w, z0.x, A0.x); A0.y = fmaf(w, z0.y, A0.y);
            A0.z = fmaf(w, z0.z, A0.z); A0.w = fmaf(w, z0.w, A0.w);
            A1.x = fmaf(w, z1.x, A1.x); A1.y = fmaf(w, z1.y, A1.y);
            A1.z = fmaf(w, z1.z, A1.z); A1.w = fmaf(w, z1.w, A1.w);
            A2.x = fmaf(w, z2.x, A2.x); A2.y = fmaf(w, z2.y, A2.y);
        }
        // self loop: + z[n] (w=1)
        float4 s0 = Z[n * 3], s1 = Z[n * 3 + 1], s2 = Z[n * 3 + 2];
        A0.x += s0.x; A0.y += s0.y; A0.z += s0.z; A0.w += s0.w;
        A1.x += s1.x; A1.y += s1.y; A1.z += s1.z; A1.w += s1.w;
        A2.x += s2.x; A2.y += s2.y;
    }

    float v[10] = { A0.x, A0.y, A0.z, A0.w, A1.x, A1.y, A1.z, A1.w, A2.x, A2.y };
    #pragma unroll
    for (int q = 0; q < 10; q++) {
        v[q] += __shfl_xor(v[q], 1);
        v[q] += __shfl_xor(v[q], 2);
        v[q] += __shfl_xor(v[q], 4);
    }

    if (k == 0) {
        float d = dis[n];
        float o = sbo;
        #pragma unroll
        for (int q = 0; q < HG; q++)
            o = fmaf(fmaf(v[q], d, sbc[q]), sWo[q], o);
        out[n] = 1.f / (1.f + __expf(-o));
    }
}

// ================= Fallback path (Round-1 scatter) =================
__global__ __launch_bounds__(256) void edge_mlp_kernel(
    const float* __restrict__ x, const float* __restrict__ token,
    const float* __restrict__ eg, const float* __restrict__ ee,
    const float* __restrict__ gum, const int* __restrict__ eidx,
    const float* __restrict__ W0, const float* __restrict__ b0,
    const float* __restrict__ W1, const float* __restrict__ b1,
    const float* __restrict__ W2, const float* __restrict__ b2,
    const float* __restrict__ W3, const float* __restrict__ b3,
    const float* __restrict__ Wl, const float* __restrict__ bl,
    float* __restrict__ ew_out, float* __restrict__ deg)
{
    __shared__ float sW0[13 * HM];
    __shared__ float sW1[HM * HM];
    __shared__ float sW2[HM * HM];
    __shared__ float sW3f[HM * 2];
    __shared__ float sb0[HM], sb1[HM], sb2[HM], sb3[2];
    __shared__ float sWl, sbl;

    for (int i = threadIdx.x; i < 13 * HM; i += 256) sW0[i] = W0[i];
    for (int i = threadIdx.x; i < HM * HM; i += 256) sW1[i] = W1[i];
    for (int i = threadIdx.x; i < HM * HM; i += 256) sW2[i] = W2[i];
    for (int i = threadIdx.x; i < HM * 2; i += 256) sW3f[i] = W3[i];
    if (threadIdx.x < HM) {
        sb0[threadIdx.x] = b0[threadIdx.x];
        sb1[threadIdx.x] = b1[threadIdx.x];
        sb2[threadIdx.x] = b2[threadIdx.x];
    }
    if (threadIdx.x < 2) sb3[threadIdx.x] = b3[threadIdx.x];
    if (threadIdx.x == 0) { sWl = Wl[0]; sbl = bl[0]; }
    __syncthreads();

    int e = blockIdx.x * 256 + threadIdx.x;
    if (e >= NE) return;
    int s = eidx[e];
    int t = eidx[NE + e];

    float ef[13];
    ef[0] = x[s];
    #pragma unroll
    for (int i = 0; i < 5; i++) ef[1 + i] = token[s * 5 + i];
    ef[6] = x[t];
    #pragma unroll
    for (int i = 0; i < 5; i++) ef[7 + i] = token[t * 5 + i];
    ef[12] = eg[e];

    float h[HM], h2[HM];
    #pragma unroll
    for (int j = 0; j < HM; j++) {
        float a = sb0[j];
        #pragma unroll
        for (int i = 0; i < 13; i++) a = fmaf(ef[i], sW0[i * HM + j], a);
        h[j] = a > 0.f ? a : 0.f;
    }
    #pragma unroll
    for (int j = 0; j < HM; j++) {
        float a = sb1[j];
        #pragma unroll
        for (int i = 0; i < HM; i++) a = fmaf(h[i], sW1[i * HM + j], a);
        h2[j] = a > 0.f ? a : 0.f;
    }
    #pragma unroll
    for (int j = 0; j < HM; j++) {
        float a = sb2[j];
        #pragma unroll
        for (int i = 0; i < HM; i++) a = fmaf(h2[i], sW2[i * HM + j], a);
        h[j] = a > 0.f ? a : 0.f;
    }
    float l0 = sb3[0], l1 = sb3[1];
    #pragma unroll
    for (int i = 0; i < HM; i++) {
        l0 = fmaf(h[i], sW3f[i * 2 + 0], l0);
        l1 = fmaf(h[i], sW3f[i * 2 + 1], l1);
    }
    const float2 g2 = ((const float2*)gum)[e];
    float v0 = l0 + g2.x, v1 = l1 + g2.y;
    float ew = 0.f;
    if (!(v1 > v0)) {
        const float2 ee2 = ((const float2*)ee)[e];
        float z = fmaf(ee2.x, sWl, sbl);
        ew = ee2.y / (1.f + __expf(-z));
    }
    ew_out[e] = ew;
    if (ew != 0.f) atomicAdd(&deg[t], ew);
}

__global__ __launch_bounds__(256) void node_pre_kernel(
    const float* __restrict__ x, const float* __restrict__ token,
    const float* __restrict__ Wc, const float* __restrict__ deg,
    float* __restrict__ xw, float* __restrict__ dis)
{
    __shared__ float sWc[6 * HG];
    if (threadIdx.x < 6 * HG) sWc[threadIdx.x] = Wc[threadIdx.x];
    __syncthreads();
    int n = blockIdx.x * 256 + threadIdx.x;
    if (n >= NN) return;
    float xa[6];
    xa[0] = x[n];
    #pragma unroll
    for (int i = 0; i < 5; i++) xa[1 + i] = token[n * 5 + i];
    #pragma unroll
    for (int k = 0; k < HG; k++) {
        float a = 0.f;
        #pragma unroll
        for (int i = 0; i < 6; i++) a = fmaf(xa[i], sWc[i * HG + k], a);
        xw[n * HG + k] = a;
    }
    dis[n] = rsqrtf(deg[n] + 1.0f);
}

__global__ __launch_bounds__(256) void edge_scatter_kernel(
    const int* __restrict__ eidx, const float* __restrict__ ew,
    const float* __restrict__ dis, const float* __restrict__ xw,
    float* __restrict__ agg)
{
    int e = blockIdx.x * 256 + threadIdx.x;
    if (e >= NE) return;
    float w = ew[e];
    if (w == 0.f) return;
    int s = eidx[e];
    int t = eidx[NE + e];
    float norm = dis[s] * w * dis[t];
    #pragma unroll
    for (int k = 0; k < HG; k++)
        atomicAdd(&agg[t * HG + k], norm * xw[s * HG + k]);
}

__global__ __launch_bounds__(256) void node_out_kernel(
    const float* __restrict__ agg, const float* __restrict__ xw,
    const float* __restrict__ dis, const float* __restrict__ bc,
    const float* __restrict__ Wo, const float* __restrict__ bo,
    float* __restrict__ out)
{
    __shared__ float sbc[HG], sWo[HG], sbo;
    if (threadIdx.x < HG) { sbc[threadIdx.x] = bc[threadIdx.x]; sWo[threadIdx.x] = Wo[threadIdx.x]; }
    if (threadIdx.x == 0) sbo = bo[0];
    __syncthreads();
    int n = blockIdx.x * 256 + threadIdx.x;
    if (n >= NN) return;
    float d = dis[n];
    float self = d * d;
    float acc = sbo;
    #pragma unroll
    for (int k = 0; k < HG; k++) {
        float v = agg[n * HG + k] + xw[n * HG + k] * self + sbc[k];
        acc = fmaf(v, sWo[k], acc);
    }
    out[n] = 1.f / (1.f + __expf(-acc));
}

extern "C" void kernel_launch(void* const* d_in, const int* in_sizes, int n_in,
                              void* d_out, int out_size, void* d_ws, size_t ws_size,
                              hipStream_t stream) {
    const float* x   = (const float*)d_in[0];
    const float* tok = (const float*)d_in[1];
    const float* eg  = (const float*)d_in[2];
    const float* ee  = (const float*)d_in[3];
    const float* gum = (const float*)d_in[4];
    const int*   ei  = (const int*)d_in[5];
    const float* W0  = (const float*)d_in[6];
    const float* b0  = (const float*)d_in[7];
    const float* W1  = (const float*)d_in[8];
    const float* b1  = (const float*)d_in[9];
    const float* W2  = (const float*)d_in[10];
    const float* b2  = (const float*)d_in[11];
    const float* W3  = (const float*)d_in[12];
    const float* b3  = (const float*)d_in[13];
    const float* Wl  = (const float*)d_in[14];
    const float* bl  = (const float*)d_in[15];
    const float* Wc  = (const float*)d_in[16];
    const float* bc  = (const float*)d_in[17];
    const float* Wo  = (const float*)d_in[18];
    const float* bo  = (const float*)d_in[19];
    float* out = (float*)d_out;

    dim3 blk(256);
    dim3 egrid(NE / 256);               // exact: 12500
    dim3 ngrid((NN + 255) / 256);
    dim3 g8grid((NN * 8 + 255) / 256);  // 8 lanes per node

    // New-path ws layout (float offsets)
    size_t off_xall8 = 0;                              // NN*8
    size_t off_xwp   = off_xall8 + (size_t)NN * 8;     // NN*12
    size_t off_slots = off_xwp + (size_t)NN * 12;      // NN*MAXK*2
    size_t off_cnt   = off_slots + (size_t)NN * MAXK * 2; // NN int
    size_t off_novf  = off_cnt + NN;                   // 1 int
    size_t off_dis   = off_novf + 1;                   // NN
    size_t off_ohead = off_dis + NN;                   // NN int
    size_t off_ovfw  = off_ohead + NN;                 // OVF_CAP
    size_t off_ovfs  = off_ovfw + OVF_CAP;             // OVF_CAP int
    size_t off_onxt  = off_ovfs + OVF_CAP;             // OVF_CAP int
    size_t off_w0t   = (off_onxt + OVF_CAP + 15) & ~(size_t)15; // 30*16
    size_t off_w1t   = off_w0t + 30 * 16;              // 30*32
    size_t off_w2t   = off_w1t + 30 * 32;              // 30*32
    size_t need_new  = (off_w2t + 30 * 32) * sizeof(float);

    if (ws_size >= need_new) {
        float*  ws    = (float*)d_ws;
        float*  xall8 = ws + off_xall8;
        float*  xwp   = ws + off_xwp;
        float2* slots = (float2*)(ws + off_slots);
        int*    cnt   = (int*)(ws + off_cnt);
        int*    novf  = (int*)(ws + off_novf);
        float*  dis   = ws + off_dis;
        int*    ohead = (int*)(ws + off_ohead);
        float*  ovf_w = ws + off_ovfw;
        int*    ovf_s = (int*)(ws + off_ovfs);
        int*    onxt  = (int*)(ws + off_onxt);
        float*  W0T   = ws + off_w0t;
        float*  W1T   = ws + off_w1t;
        float*  W2T   = ws + off_w2t;

        hipMemsetAsync(cnt, 0, (size_t)(NN + 1) * sizeof(int), stream);   // cnt + novf
        hipMemsetAsync(ohead, 0xFF, (size_t)NN * sizeof(int), stream);    // ohead = -1

        wtrans_kernel<<<dim3(1), blk, 0, stream>>>(W0, W1, W2, W0T, W1T, W2T);
        pack_kernel<<<ngrid, blk, 0, stream>>>(x, tok, Wc, xall8, xwp);
        edge_mlp9_kernel<<<egrid, blk, 0, stream>>>(xall8, eg, ee, gum, ei,
                                                    W0T, b0, W1T, b1, W2T, b2,
                                                    W3, b3, Wl, bl, slots, cnt,
                                                    ohead, onxt, ovf_w, ovf_s, novf);
        node_deg_kernel<<<ngrid, blk, 0, stream>>>(slots, cnt, ohead, onxt, ovf_w,
                                                   xwp, dis);
        gather_out5_kernel<<<g8grid, blk, 0, stream>>>(slots, cnt, ohead, onxt,
                                                       ovf_w, ovf_s, xwp, dis,
                                                       bc, Wo, bo, out);
    } else {
        // Fallback: Round-1 scatter layout: [ew: NE][deg: NN][agg: NN*HG][xw: NN*HG][dis: NN]
        float* ws  = (float*)d_ws;
        float* ew  = ws;
        float* deg = ew + NE;
        float* agg = deg + NN;
        float* xw  = agg + (size_t)NN * HG;
        float* dis = xw + (size_t)NN * HG;

        hipMemsetAsync(deg, 0, (size_t)(NN + (size_t)NN * HG) * sizeof(float), stream);
        edge_mlp_kernel<<<egrid, blk, 0, stream>>>(x, tok, eg, ee, gum, ei,
                                                   W0, b0, W1, b1, W2, b2, W3, b3,
                                                   Wl, bl, ew, deg);
        node_pre_kernel<<<ngrid, blk, 0, stream>>>(x, tok, Wc, deg, xw, dis);
        edge_scatter_kernel<<<egrid, blk, 0, stream>>>(ei, ew, dis, xw, agg);
        node_out_kernel<<<ngrid, blk, 0, stream>>>(agg, xw, dis, bc, Wo, bo, out);
    }
}

// Round 11
// 372.185 us; speedup vs baseline: 1.7109x; 1.0332x over previous
//
#include <hip/hip_runtime.h>

#define NN 100000
#define NE 3200000
#define HM 30
#define HG 10
#define MAXK 26
#define OVF_CAP 8192

typedef float __attribute__((ext_vector_type(2))) f32x2;

__device__ __forceinline__ f32x2 pkfma(f32x2 a, f32x2 b, f32x2 c) {
#if __has_builtin(__builtin_elementwise_fma)
    return __builtin_elementwise_fma(a, b, c);
#else
    f32x2 r; r.x = fmaf(a.x, b.x, c.x); r.y = fmaf(a.y, b.y, c.y); return r;
#endif
}

// ---------------- Stage -1: transpose+pad weights into ws ----------------
__global__ __launch_bounds__(256) void wtrans_kernel(
    const float* __restrict__ W0, const float* __restrict__ W1,
    const float* __restrict__ W2,
    float* __restrict__ W0T, float* __restrict__ W1T, float* __restrict__ W2T)
{
    for (int idx = threadIdx.x; idx < HM * 16; idx += 256) {
        int j = idx >> 4, i = idx & 15;
        W0T[idx] = (i < 13) ? W0[i * HM + j] : 0.f;
    }
    for (int idx = threadIdx.x; idx < HM * 32; idx += 256) {
        int j = idx >> 5, i = idx & 31;
        float v1 = (i < HM) ? W1[i * HM + j] : 0.f;
        float v2 = (i < HM) ? W2[i * HM + j] : 0.f;
        W1T[idx] = v1;
        W2T[idx] = v2;
    }
}

// ---------------- Stage 0: pack node features + xw ----------------
__global__ __launch_bounds__(256) void pack_kernel(
    const float* __restrict__ x, const float* __restrict__ token,
    const float* __restrict__ Wc,
    float* __restrict__ xall8, float* __restrict__ xwp)
{
    __shared__ float sWc[6 * HG];
    if (threadIdx.x < 6 * HG) sWc[threadIdx.x] = Wc[threadIdx.x];
    __syncthreads();

    int n = blockIdx.x * 256 + threadIdx.x;
    if (n >= NN) return;

    float xa[6];
    xa[0] = x[n];
    #pragma unroll
    for (int i = 0; i < 5; i++) xa[1 + i] = token[n * 5 + i];

    float4* x4 = (float4*)xall8;
    x4[n * 2 + 0] = make_float4(xa[0], xa[1], xa[2], xa[3]);
    x4[n * 2 + 1] = make_float4(xa[4], xa[5], 0.f, 0.f);

    float w[12];
    #pragma unroll
    for (int k = 0; k < HG; k++) {
        float a = 0.f;
        #pragma unroll
        for (int i = 0; i < 6; i++) a = fmaf(xa[i], sWc[i * HG + k], a);
        w[k] = a;
    }
    w[10] = 0.f; w[11] = 0.f;
    float4* wp = (float4*)(xwp + (size_t)n * 12);
    wp[0] = make_float4(w[0], w[1], w[2], w[3]);
    wp[1] = make_float4(w[4], w[5], w[6], w[7]);
    wp[2] = make_float4(w[8], w[9], w[10], w[11]);
}

// ---------------- Stage 1: per-edge MLP (pk scalar weights) ----------------
// Best measured edge form (round 8: 208us). 1 edge/thread, pure-SMEM
// weights (W^T pk pairs), no deg atomic. KNOWN LAWS from rounds 1-10:
//  - >~90 live VGPRs -> allocator parks state in AGPRs, 2-3x VALU churn
//    (rounds 1/4/9). 2-edge forms are dead.
//  - SMEM weight stream has a ~140us bandwidth floor (11.5KB/wave-batch);
//    invariant across scalar/pk/wide-load forms (rounds 3/5/8).
//  - SMEM+LDS split does NOT overlap: shared lgkmcnt + OOO SMEM returns
//    drain both queues at every wait (round 10: 223us > 208us).
//  - deg atomicAdd costs ~116MB cross-XCD line traffic (round 7).
__global__ __launch_bounds__(256, 2) void edge_mlp7_kernel(
    const float* __restrict__ xall8,
    const float* __restrict__ eg, const float* __restrict__ ee,
    const float* __restrict__ gum, const int* __restrict__ eidx,
    const float* __restrict__ W0T, const float* __restrict__ b0,
    const float* __restrict__ W1T, const float* __restrict__ b1,
    const float* __restrict__ W2T, const float* __restrict__ b2,
    const float* __restrict__ W3, const float* __restrict__ b3,
    const float* __restrict__ Wl, const float* __restrict__ bl,
    float2* __restrict__ slots, int* __restrict__ cnt,
    int* __restrict__ ohead, int* __restrict__ onxt,
    float* __restrict__ ovf_w, int* __restrict__ ovf_s, int* __restrict__ novf)
{
    int e = blockIdx.x * 256 + threadIdx.x;   // NE == 12500*256 exactly
    int s = eidx[e];
    int t = eidx[NE + e];

    const float4* x4 = (const float4*)xall8;
    float4 qa = x4[s * 2], qb = x4[s * 2 + 1];
    float4 qc = x4[t * 2], qd = x4[t * 2 + 1];

    f32x2 ef2[7];
    ef2[0] = f32x2{ qa.x, qa.y };
    ef2[1] = f32x2{ qa.z, qa.w };
    ef2[2] = f32x2{ qb.x, qb.y };
    ef2[3] = f32x2{ qc.x, qc.y };
    ef2[4] = f32x2{ qc.z, qc.w };
    ef2[5] = f32x2{ qd.x, qd.y };
    ef2[6] = f32x2{ eg[e], 0.f };

    float h[HM], g[HM];

    #pragma unroll
    for (int j = 0; j < HM; j++) {
        const f32x2* w2 = (const f32x2*)(W0T + j * 16);
        f32x2 a2 = f32x2{ b0[j], 0.f };
        #pragma unroll
        for (int p = 0; p < 7; p++) a2 = pkfma(ef2[p], w2[p], a2);
        h[j] = fmaxf(a2.x + a2.y, 0.f);
    }

    {
        f32x2 hp[15];
        #pragma unroll
        for (int p = 0; p < 15; p++) hp[p] = f32x2{ h[2 * p], h[2 * p + 1] };
        #pragma unroll
        for (int j = 0; j < HM; j++) {
            const f32x2* w2 = (const f32x2*)(W1T + j * 32);
            f32x2 a2 = f32x2{ b1[j], 0.f };
            #pragma unroll
            for (int p = 0; p < 15; p++) a2 = pkfma(hp[p], w2[p], a2);
            g[j] = fmaxf(a2.x + a2.y, 0.f);
        }
    }
    {
        f32x2 gp[15];
        #pragma unroll
        for (int p = 0; p < 15; p++) gp[p] = f32x2{ g[2 * p], g[2 * p + 1] };
        #pragma unroll
        for (int j = 0; j < HM; j++) {
            const f32x2* w2 = (const f32x2*)(W2T + j * 32);
            f32x2 a2 = f32x2{ b2[j], 0.f };
            #pragma unroll
            for (int p = 0; p < 15; p++) a2 = pkfma(gp[p], w2[p], a2);
            h[j] = fmaxf(a2.x + a2.y, 0.f);
        }
    }

    float l0 = b3[0], l1 = b3[1];
    #pragma unroll
    for (int i = 0; i < HM; i++) {
        l0 = fmaf(h[i], W3[i * 2 + 0], l0);
        l1 = fmaf(h[i], W3[i * 2 + 1], l1);
    }

    const float2 g2 = ((const float2*)gum)[e];
    float v0 = l0 + g2.x;
    float v1 = l1 + g2.y;

    // forward: edge_value = (v1 > v0) ? 1 : 0; active iff edge_value == 0
    float ew = 0.f;
    if (!(v1 > v0)) {
        const float2 e2 = ((const float2*)ee)[e];
        float z = fmaf(e2.x, Wl[0], bl[0]);
        ew = e2.y / (1.f + __expf(-z));
    }
    if (ew != 0.f) {
        int slot = atomicAdd(&cnt[t], 1);
        if (slot < MAXK) {
            slots[(size_t)t * MAXK + slot] = make_float2(ew, __int_as_float(s));
        } else {
            int i = atomicAdd(novf, 1);
            if (i < OVF_CAP) {
                ovf_w[i] = ew;
                ovf_s[i] = s;
                onxt[i] = atomicExch(&ohead[t], i);
            }
        }
    }
}

// ---------------- Stage 2: per-node deg -> dis; scale xwp in place to z ----
__global__ __launch_bounds__(256) void node_deg_kernel(
    const float2* __restrict__ slots, const int* __restrict__ cnt,
    const int* __restrict__ ohead, const int* __restrict__ onxt,
    const float* __restrict__ ovf_w,
    float* __restrict__ xwp, float* __restrict__ dis)
{
    int n = blockIdx.x * 256 + threadIdx.x;
    if (n >= NN) return;

    int c = cnt[n];
    int cc = c < MAXK ? c : MAXK;
    float deg = 0.f;
    for (int j = 0; j < cc; j++) deg += slots[(size_t)n * MAXK + j].x;
    for (int i = ohead[n]; i >= 0; i = onxt[i]) deg += ovf_w[i];

    float d = rsqrtf(deg + 1.0f);   // +1 = self loop
    dis[n] = d;

    float4* wp = (float4*)(xwp + (size_t)n * 12);
    #pragma unroll
    for (int q = 0; q < 3; q++) {
        float4 v = wp[q];
        v.x *= d; v.y *= d; v.z *= d; v.w *= d;
        wp[q] = v;
    }
}

// ---------------- Stage 3: gather, 8 lanes per node, pre-scaled z ----------
// Round-9 differential: 8-lane tail = 154us vs 167us with 4-lane.
__global__ __launch_bounds__(256) void gather_out5_kernel(
    const float2* __restrict__ slots, const int* __restrict__ cnt,
    const int* __restrict__ ohead, const int* __restrict__ onxt,
    const float* __restrict__ ovf_w, const int* __restrict__ ovf_s,
    const float* __restrict__ z, const float* __restrict__ dis,
    const float* __restrict__ bc, const float* __restrict__ Wo,
    const float* __restrict__ bo, float* __restrict__ out)
{
    __shared__ float sbc[12], sWo[12], sbo;
    if (threadIdx.x < 12) {
        sbc[threadIdx.x] = (threadIdx.x < HG) ? bc[threadIdx.x] : 0.f;
        sWo[threadIdx.x] = (threadIdx.x < HG) ? Wo[threadIdx.x] : 0.f;
    }
    if (threadIdx.x == 0) sbo = bo[0];
    __syncthreads();

    int tg = blockIdx.x * 256 + threadIdx.x;
    int n = tg >> 3;
    int k = tg & 7;
    if (n >= NN) return;

    const float4* Z = (const float4*)z;
    float4 A0 = make_float4(0.f, 0.f, 0.f, 0.f), A1 = A0, A2 = A0;

    int c = cnt[n];
    int cc = c < MAXK ? c : MAXK;
    for (int j = k; j < cc; j += 8) {
        float2 p = slots[(size_t)n * MAXK + j];
        float w = p.x;
        int s = __float_as_int(p.y);
        float4 z0 = Z[s * 3], z1 = Z[s * 3 + 1], z2 = Z[s * 3 + 2];
        A0.x = fmaf(w, z0.x, A0.x); A0.y = fmaf(w, z0.y, A0.y);
        A0.z = fmaf(w, z0.z, A0.z); A0.w = fmaf(w, z0.w, A0.w);
        A1.x = fmaf(w, z1.x, A1.x); A1.y = fmaf(w, z1.y, A1.y);
        A1.z = fmaf(w, z1.z, A1.z); A1.w = fmaf(w, z1.w, A1.w);
        A2.x = fmaf(w, z2.x, A2.x); A2.y = fmaf(w, z2.y, A2.y);
    }
    if (k == 0) {
        for (int i = ohead[n]; i >= 0; i = onxt[i]) {
            float w = ovf_w[i];
            int s = ovf_s[i];
            float4 z0 = Z[s * 3], z1 = Z[s * 3 + 1], z2 = Z[s * 3 + 2];
            A0.x = fmaf(w, z0.x, A0.x); A0.y = fmaf(w, z0.y, A0.y);
            A0.z = fmaf(w, z0.z, A0.z); A0.w = fmaf(w, z0.w, A0.w);
            A1.x = fmaf(w, z1.x, A1.x); A1.y = fmaf(w, z1.y, A1.y);
            A1.z = fmaf(w, z1.z, A1.z); A1.w = fmaf(w, z1.w, A1.w);
            A2.x = fmaf(w, z2.x, A2.x); A2.y = fmaf(w, z2.y, A2.y);
        }
        // self loop: + z[n] (w=1)
        float4 s0 = Z[n * 3], s1 = Z[n * 3 + 1], s2 = Z[n * 3 + 2];
        A0.x += s0.x; A0.y += s0.y; A0.z += s0.z; A0.w += s0.w;
        A1.x += s1.x; A1.y += s1.y; A1.z += s1.z; A1.w += s1.w;
        A2.x += s2.x; A2.y += s2.y;
    }

    float v[10] = { A0.x, A0.y, A0.z, A0.w, A1.x, A1.y, A1.z, A1.w, A2.x, A2.y };
    #pragma unroll
    for (int q = 0; q < 10; q++) {
        v[q] += __shfl_xor(v[q], 1);
        v[q] += __shfl_xor(v[q], 2);
        v[q] += __shfl_xor(v[q], 4);
    }

    if (k == 0) {
        float d = dis[n];
        float o = sbo;
        #pragma unroll
        for (int q = 0; q < HG; q++)
            o = fmaf(fmaf(v[q], d, sbc[q]), sWo[q], o);
        out[n] = 1.f / (1.f + __expf(-o));
    }
}

// ================= Fallback path (Round-1 scatter) =================
__global__ __launch_bounds__(256) void edge_mlp_kernel(
    const float* __restrict__ x, const float* __restrict__ token,
    const float* __restrict__ eg, const float* __restrict__ ee,
    const float* __restrict__ gum, const int* __restrict__ eidx,
    const float* __restrict__ W0, const float* __restrict__ b0,
    const float* __restrict__ W1, const float* __restrict__ b1,
    const float* __restrict__ W2, const float* __restrict__ b2,
    const float* __restrict__ W3, const float* __restrict__ b3,
    const float* __restrict__ Wl, const float* __restrict__ bl,
    float* __restrict__ ew_out, float* __restrict__ deg)
{
    __shared__ float sW0[13 * HM];
    __shared__ float sW1[HM * HM];
    __shared__ float sW2[HM * HM];
    __shared__ float sW3f[HM * 2];
    __shared__ float sb0[HM], sb1[HM], sb2[HM], sb3[2];
    __shared__ float sWl, sbl;

    for (int i = threadIdx.x; i < 13 * HM; i += 256) sW0[i] = W0[i];
    for (int i = threadIdx.x; i < HM * HM; i += 256) sW1[i] = W1[i];
    for (int i = threadIdx.x; i < HM * HM; i += 256) sW2[i] = W2[i];
    for (int i = threadIdx.x; i < HM * 2; i += 256) sW3f[i] = W3[i];
    if (threadIdx.x < HM) {
        sb0[threadIdx.x] = b0[threadIdx.x];
        sb1[threadIdx.x] = b1[threadIdx.x];
        sb2[threadIdx.x] = b2[threadIdx.x];
    }
    if (threadIdx.x < 2) sb3[threadIdx.x] = b3[threadIdx.x];
    if (threadIdx.x == 0) { sWl = Wl[0]; sbl = bl[0]; }
    __syncthreads();

    int e = blockIdx.x * 256 + threadIdx.x;
    if (e >= NE) return;
    int s = eidx[e];
    int t = eidx[NE + e];

    float ef[13];
    ef[0] = x[s];
    #pragma unroll
    for (int i = 0; i < 5; i++) ef[1 + i] = token[s * 5 + i];
    ef[6] = x[t];
    #pragma unroll
    for (int i = 0; i < 5; i++) ef[7 + i] = token[t * 5 + i];
    ef[12] = eg[e];

    float h[HM], h2[HM];
    #pragma unroll
    for (int j = 0; j < HM; j++) {
        float a = sb0[j];
        #pragma unroll
        for (int i = 0; i < 13; i++) a = fmaf(ef[i], sW0[i * HM + j], a);
        h[j] = a > 0.f ? a : 0.f;
    }
    #pragma unroll
    for (int j = 0; j < HM; j++) {
        float a = sb1[j];
        #pragma unroll
        for (int i = 0; i < HM; i++) a = fmaf(h[i], sW1[i * HM + j], a);
        h2[j] = a > 0.f ? a : 0.f;
    }
    #pragma unroll
    for (int j = 0; j < HM; j++) {
        float a = sb2[j];
        #pragma unroll
        for (int i = 0; i < HM; i++) a = fmaf(h2[i], sW2[i * HM + j], a);
        h[j] = a > 0.f ? a : 0.f;
    }
    float l0 = sb3[0], l1 = sb3[1];
    #pragma unroll
    for (int i = 0; i < HM; i++) {
        l0 = fmaf(h[i], sW3f[i * 2 + 0], l0);
        l1 = fmaf(h[i], sW3f[i * 2 + 1], l1);
    }
    const float2 g2 = ((const float2*)gum)[e];
    float v0 = l0 + g2.x, v1 = l1 + g2.y;
    float ew = 0.f;
    if (!(v1 > v0)) {
        const float2 ee2 = ((const float2*)ee)[e];
        float z = fmaf(ee2.x, sWl, sbl);
        ew = ee2.y / (1.f + __expf(-z));
    }
    ew_out[e] = ew;
    if (ew != 0.f) atomicAdd(&deg[t], ew);
}

__global__ __launch_bounds__(256) void node_pre_kernel(
    const float* __restrict__ x, const float* __restrict__ token,
    const float* __restrict__ Wc, const float* __restrict__ deg,
    float* __restrict__ xw, float* __restrict__ dis)
{
    __shared__ float sWc[6 * HG];
    if (threadIdx.x < 6 * HG) sWc[threadIdx.x] = Wc[threadIdx.x];
    __syncthreads();
    int n = blockIdx.x * 256 + threadIdx.x;
    if (n >= NN) return;
    float xa[6];
    xa[0] = x[n];
    #pragma unroll
    for (int i = 0; i < 5; i++) xa[1 + i] = token[n * 5 + i];
    #pragma unroll
    for (int k = 0; k < HG; k++) {
        float a = 0.f;
        #pragma unroll
        for (int i = 0; i < 6; i++) a = fmaf(xa[i], sWc[i * HG + k], a);
        xw[n * HG + k] = a;
    }
    dis[n] = rsqrtf(deg[n] + 1.0f);
}

__global__ __launch_bounds__(256) void edge_scatter_kernel(
    const int* __restrict__ eidx, const float* __restrict__ ew,
    const float* __restrict__ dis, const float* __restrict__ xw,
    float* __restrict__ agg)
{
    int e = blockIdx.x * 256 + threadIdx.x;
    if (e >= NE) return;
    float w = ew[e];
    if (w == 0.f) return;
    int s = eidx[e];
    int t = eidx[NE + e];
    float norm = dis[s] * w * dis[t];
    #pragma unroll
    for (int k = 0; k < HG; k++)
        atomicAdd(&agg[t * HG + k], norm * xw[s * HG + k]);
}

__global__ __launch_bounds__(256) void node_out_kernel(
    const float* __restrict__ agg, const float* __restrict__ xw,
    const float* __restrict__ dis, const float* __restrict__ bc,
    const float* __restrict__ Wo, const float* __restrict__ bo,
    float* __restrict__ out)
{
    __shared__ float sbc[HG], sWo[HG], sbo;
    if (threadIdx.x < HG) { sbc[threadIdx.x] = bc[threadIdx.x]; sWo[threadIdx.x] = Wo[threadIdx.x]; }
    if (threadIdx.x == 0) sbo = bo[0];
    __syncthreads();
    int n = blockIdx.x * 256 + threadIdx.x;
    if (n >= NN) return;
    float d = dis[n];
    float self = d * d;
    float acc = sbo;
    #pragma unroll
    for (int k = 0; k < HG; k++) {
        float v = agg[n * HG + k] + xw[n * HG + k] * self + sbc[k];
        acc = fmaf(v, sWo[k], acc);
    }
    out[n] = 1.f / (1.f + __expf(-acc));
}

extern "C" void kernel_launch(void* const* d_in, const int* in_sizes, int n_in,
                              void* d_out, int out_size, void* d_ws, size_t ws_size,
                              hipStream_t stream) {
    const float* x   = (const float*)d_in[0];
    const float* tok = (const float*)d_in[1];
    const float* eg  = (const float*)d_in[2];
    const float* ee  = (const float*)d_in[3];
    const float* gum = (const float*)d_in[4];
    const int*   ei  = (const int*)d_in[5];
    const float* W0  = (const float*)d_in[6];
    const float* b0  = (const float*)d_in[7];
    const float* W1  = (const float*)d_in[8];
    const float* b1  = (const float*)d_in[9];
    const float* W2  = (const float*)d_in[10];
    const float* b2  = (const float*)d_in[11];
    const float* W3  = (const float*)d_in[12];
    const float* b3  = (const float*)d_in[13];
    const float* Wl  = (const float*)d_in[14];
    const float* bl  = (const float*)d_in[15];
    const float* Wc  = (const float*)d_in[16];
    const float* bc  = (const float*)d_in[17];
    const float* Wo  = (const float*)d_in[18];
    const float* bo  = (const float*)d_in[19];
    float* out = (float*)d_out;

    dim3 blk(256);
    dim3 egrid(NE / 256);               // exact: 12500
    dim3 ngrid((NN + 255) / 256);
    dim3 g8grid((NN * 8 + 255) / 256);  // 8 lanes per node

    // New-path ws layout (float offsets)
    size_t off_xall8 = 0;                              // NN*8
    size_t off_xwp   = off_xall8 + (size_t)NN * 8;     // NN*12
    size_t off_slots = off_xwp + (size_t)NN * 12;      // NN*MAXK*2
    size_t off_cnt   = off_slots + (size_t)NN * MAXK * 2; // NN int
    size_t off_novf  = off_cnt + NN;                   // 1 int
    size_t off_dis   = off_novf + 1;                   // NN
    size_t off_ohead = off_dis + NN;                   // NN int
    size_t off_ovfw  = off_ohead + NN;                 // OVF_CAP
    size_t off_ovfs  = off_ovfw + OVF_CAP;             // OVF_CAP int
    size_t off_onxt  = off_ovfs + OVF_CAP;             // OVF_CAP int
    size_t off_w0t   = (off_onxt + OVF_CAP + 15) & ~(size_t)15; // 30*16
    size_t off_w1t   = off_w0t + 30 * 16;              // 30*32
    size_t off_w2t   = off_w1t + 30 * 32;              // 30*32
    size_t need_new  = (off_w2t + 30 * 32) * sizeof(float);

    if (ws_size >= need_new) {
        float*  ws    = (float*)d_ws;
        float*  xall8 = ws + off_xall8;
        float*  xwp   = ws + off_xwp;
        float2* slots = (float2*)(ws + off_slots);
        int*    cnt   = (int*)(ws + off_cnt);
        int*    novf  = (int*)(ws + off_novf);
        float*  dis   = ws + off_dis;
        int*    ohead = (int*)(ws + off_ohead);
        float*  ovf_w = ws + off_ovfw;
        int*    ovf_s = (int*)(ws + off_ovfs);
        int*    onxt  = (int*)(ws + off_onxt);
        float*  W0T   = ws + off_w0t;
        float*  W1T   = ws + off_w1t;
        float*  W2T   = ws + off_w2t;

        hipMemsetAsync(cnt, 0, (size_t)(NN + 1) * sizeof(int), stream);   // cnt + novf
        hipMemsetAsync(ohead, 0xFF, (size_t)NN * sizeof(int), stream);    // ohead = -1

        wtrans_kernel<<<dim3(1), blk, 0, stream>>>(W0, W1, W2, W0T, W1T, W2T);
        pack_kernel<<<ngrid, blk, 0, stream>>>(x, tok, Wc, xall8, xwp);
        edge_mlp7_kernel<<<egrid, blk, 0, stream>>>(xall8, eg, ee, gum, ei,
                                                    W0T, b0, W1T, b1, W2T, b2,
                                                    W3, b3, Wl, bl, slots, cnt,
                                                    ohead, onxt, ovf_w, ovf_s, novf);
        node_deg_kernel<<<ngrid, blk, 0, stream>>>(slots, cnt, ohead, onxt, ovf_w,
                                                   xwp, dis);
        gather_out5_kernel<<<g8grid, blk, 0, stream>>>(slots, cnt, ohead, onxt,
                                                       ovf_w, ovf_s, xwp, dis,
                                                       bc, Wo, bo, out);
    } else {
        // Fallback: Round-1 scatter layout: [ew: NE][deg: NN][agg: NN*HG][xw: NN*HG][dis: NN]
        float* ws  = (float*)d_ws;
        float* ew  = ws;
        float* deg = ew + NE;
        float* agg = deg + NN;
        float* xw  = agg + (size_t)NN * HG;
        float* dis = xw + (size_t)NN * HG;

        hipMemsetAsync(deg, 0, (size_t)(NN + (size_t)NN * HG) * sizeof(float), stream);
        edge_mlp_kernel<<<egrid, blk, 0, stream>>>(x, tok, eg, ee, gum, ei,
                                                   W0, b0, W1, b1, W2, b2, W3, b3,
                                                   Wl, bl, ew, deg);
        node_pre_kernel<<<ngrid, blk, 0, stream>>>(x, tok, Wc, deg, xw, dis);
        edge_scatter_kernel<<<egrid, blk, 0, stream>>>(ei, ew, dis, xw, agg);
        node_out_kernel<<<ngrid, blk, 0, stream>>>(agg, xw, dis, bc, Wo, bo, out);
    }
}

// Round 12
// 371.017 us; speedup vs baseline: 1.7163x; 1.0031x over previous
//
#include <hip/hip_runtime.h>

#define NN 100000
#define NE 3200000
#define HM 30
#define HG 10
#define MAXK 26
#define OVF_CAP 8192

typedef float __attribute__((ext_vector_type(2))) f32x2;

__device__ __forceinline__ f32x2 pkfma(f32x2 a, f32x2 b, f32x2 c) {
#if __has_builtin(__builtin_elementwise_fma)
    return __builtin_elementwise_fma(a, b, c);
#else
    f32x2 r; r.x = fmaf(a.x, b.x, c.x); r.y = fmaf(a.y, b.y, c.y); return r;
#endif
}

// ---------------- Stage -1: transpose+pad weights into ws ----------------
__global__ __launch_bounds__(256) void wtrans_kernel(
    const float* __restrict__ W0, const float* __restrict__ W1,
    const float* __restrict__ W2,
    float* __restrict__ W0T, float* __restrict__ W1T, float* __restrict__ W2T)
{
    for (int idx = threadIdx.x; idx < HM * 16; idx += 256) {
        int j = idx >> 4, i = idx & 15;
        W0T[idx] = (i < 13) ? W0[i * HM + j] : 0.f;
    }
    for (int idx = threadIdx.x; idx < HM * 32; idx += 256) {
        int j = idx >> 5, i = idx & 31;
        float v1 = (i < HM) ? W1[i * HM + j] : 0.f;
        float v2 = (i < HM) ? W2[i * HM + j] : 0.f;
        W1T[idx] = v1;
        W2T[idx] = v2;
    }
}

// ---------------- Stage 0: pack node features + xw ----------------
// zr = float4s per xwp row (4 = 64B-aligned rows, 3 = legacy 48B).
__global__ __launch_bounds__(256) void pack_kernel(
    const float* __restrict__ x, const float* __restrict__ token,
    const float* __restrict__ Wc,
    float* __restrict__ xall8, float* __restrict__ xwp, int zr)
{
    __shared__ float sWc[6 * HG];
    if (threadIdx.x < 6 * HG) sWc[threadIdx.x] = Wc[threadIdx.x];
    __syncthreads();

    int n = blockIdx.x * 256 + threadIdx.x;
    if (n >= NN) return;

    float xa[6];
    xa[0] = x[n];
    #pragma unroll
    for (int i = 0; i < 5; i++) xa[1 + i] = token[n * 5 + i];

    float4* x4 = (float4*)xall8;
    x4[n * 2 + 0] = make_float4(xa[0], xa[1], xa[2], xa[3]);
    x4[n * 2 + 1] = make_float4(xa[4], xa[5], 0.f, 0.f);

    float w[12];
    #pragma unroll
    for (int k = 0; k < HG; k++) {
        float a = 0.f;
        #pragma unroll
        for (int i = 0; i < 6; i++) a = fmaf(xa[i], sWc[i * HG + k], a);
        w[k] = a;
    }
    w[10] = 0.f; w[11] = 0.f;
    float4* wp = (float4*)xwp + (size_t)n * zr;
    wp[0] = make_float4(w[0], w[1], w[2], w[3]);
    wp[1] = make_float4(w[4], w[5], w[6], w[7]);
    wp[2] = make_float4(w[8], w[9], w[10], w[11]);
}

// ---------------- Stage 1: per-edge MLP (pk scalar weights) ----------------
// Best measured edge form (round 8/11: 208us). 1 edge/thread, pure-SMEM
// weights (W^T pk pairs), no deg atomic. KNOWN LAWS from rounds 1-11:
//  - >~90 live VGPRs -> allocator parks state in AGPRs, 2-3x VALU churn
//    (rounds 1/4/9). 2-edge forms are dead.
//  - SMEM weight stream has a ~140us floor; invariant across
//    scalar/pk/wide-load forms (rounds 3/5/8).
//  - SMEM+LDS split does NOT overlap (shared lgkmcnt, round 10).
//  - deg atomicAdd costs ~116MB cross-XCD line traffic (round 7).
__global__ __launch_bounds__(256, 2) void edge_mlp7_kernel(
    const float* __restrict__ xall8,
    const float* __restrict__ eg, const float* __restrict__ ee,
    const float* __restrict__ gum, const int* __restrict__ eidx,
    const float* __restrict__ W0T, const float* __restrict__ b0,
    const float* __restrict__ W1T, const float* __restrict__ b1,
    const float* __restrict__ W2T, const float* __restrict__ b2,
    const float* __restrict__ W3, const float* __restrict__ b3,
    const float* __restrict__ Wl, const float* __restrict__ bl,
    float2* __restrict__ slots, int* __restrict__ cnt,
    int* __restrict__ ohead, int* __restrict__ onxt,
    float* __restrict__ ovf_w, int* __restrict__ ovf_s, int* __restrict__ novf)
{
    int e = blockIdx.x * 256 + threadIdx.x;   // NE == 12500*256 exactly
    int s = eidx[e];
    int t = eidx[NE + e];

    const float4* x4 = (const float4*)xall8;
    float4 qa = x4[s * 2], qb = x4[s * 2 + 1];
    float4 qc = x4[t * 2], qd = x4[t * 2 + 1];

    f32x2 ef2[7];
    ef2[0] = f32x2{ qa.x, qa.y };
    ef2[1] = f32x2{ qa.z, qa.w };
    ef2[2] = f32x2{ qb.x, qb.y };
    ef2[3] = f32x2{ qc.x, qc.y };
    ef2[4] = f32x2{ qc.z, qc.w };
    ef2[5] = f32x2{ qd.x, qd.y };
    ef2[6] = f32x2{ eg[e], 0.f };

    float h[HM], g[HM];

    #pragma unroll
    for (int j = 0; j < HM; j++) {
        const f32x2* w2 = (const f32x2*)(W0T + j * 16);
        f32x2 a2 = f32x2{ b0[j], 0.f };
        #pragma unroll
        for (int p = 0; p < 7; p++) a2 = pkfma(ef2[p], w2[p], a2);
        h[j] = fmaxf(a2.x + a2.y, 0.f);
    }

    {
        f32x2 hp[15];
        #pragma unroll
        for (int p = 0; p < 15; p++) hp[p] = f32x2{ h[2 * p], h[2 * p + 1] };
        #pragma unroll
        for (int j = 0; j < HM; j++) {
            const f32x2* w2 = (const f32x2*)(W1T + j * 32);
            f32x2 a2 = f32x2{ b1[j], 0.f };
            #pragma unroll
            for (int p = 0; p < 15; p++) a2 = pkfma(hp[p], w2[p], a2);
            g[j] = fmaxf(a2.x + a2.y, 0.f);
        }
    }
    {
        f32x2 gp[15];
        #pragma unroll
        for (int p = 0; p < 15; p++) gp[p] = f32x2{ g[2 * p], g[2 * p + 1] };
        #pragma unroll
        for (int j = 0; j < HM; j++) {
            const f32x2* w2 = (const f32x2*)(W2T + j * 32);
            f32x2 a2 = f32x2{ b2[j], 0.f };
            #pragma unroll
            for (int p = 0; p < 15; p++) a2 = pkfma(gp[p], w2[p], a2);
            h[j] = fmaxf(a2.x + a2.y, 0.f);
        }
    }

    float l0 = b3[0], l1 = b3[1];
    #pragma unroll
    for (int i = 0; i < HM; i++) {
        l0 = fmaf(h[i], W3[i * 2 + 0], l0);
        l1 = fmaf(h[i], W3[i * 2 + 1], l1);
    }

    const float2 g2 = ((const float2*)gum)[e];
    float v0 = l0 + g2.x;
    float v1 = l1 + g2.y;

    // forward: edge_value = (v1 > v0) ? 1 : 0; active iff edge_value == 0
    float ew = 0.f;
    if (!(v1 > v0)) {
        const float2 e2 = ((const float2*)ee)[e];
        float z = fmaf(e2.x, Wl[0], bl[0]);
        ew = e2.y / (1.f + __expf(-z));
    }
    if (ew != 0.f) {
        int slot = atomicAdd(&cnt[t], 1);
        if (slot < MAXK) {
            slots[(size_t)t * MAXK + slot] = make_float2(ew, __int_as_float(s));
        } else {
            int i = atomicAdd(novf, 1);
            if (i < OVF_CAP) {
                ovf_w[i] = ew;
                ovf_s[i] = s;
                onxt[i] = atomicExch(&ohead[t], i);
            }
        }
    }
}

// ---------------- Stage 2: deg -> dis; scale xwp to z (4 lanes/node) ------
// Round-11 analysis: per-thread-row slot reads are 8B @ 208B stride across
// lanes = uncoalesced. 4 lanes/node: lanes read adjacent float2s (32B
// chunks), group-reduced with shfl_xor; overflow walked on lane 0 BEFORE
// the shuffle so all lanes get the full deg.
__global__ __launch_bounds__(256) void node_deg4_kernel(
    const float2* __restrict__ slots, const int* __restrict__ cnt,
    const int* __restrict__ ohead, const int* __restrict__ onxt,
    const float* __restrict__ ovf_w,
    float* __restrict__ xwp, float* __restrict__ dis, int zr)
{
    int tg = blockIdx.x * 256 + threadIdx.x;
    int n = tg >> 2;
    int k = tg & 3;
    if (n >= NN) return;

    int c = cnt[n];
    int cc = c < MAXK ? c : MAXK;
    float deg = 0.f;
    for (int j = k; j < cc; j += 4) deg += slots[(size_t)n * MAXK + j].x;
    if (k == 0)
        for (int i = ohead[n]; i >= 0; i = onxt[i]) deg += ovf_w[i];

    deg += __shfl_xor(deg, 1);
    deg += __shfl_xor(deg, 2);

    float d = rsqrtf(deg + 1.0f);   // +1 = self loop
    if (k == 0) dis[n] = d;

    if (k < 3) {
        float4* wp = (float4*)xwp + (size_t)n * zr;
        float4 v = wp[k];
        v.x *= d; v.y *= d; v.z *= d; v.w *= d;
        wp[k] = v;
    }
}

// ---------------- Stage 3: gather, 8 lanes per node, pre-scaled z ----------
// Round-9 differential: 8-lane tail beat 4-lane by ~13us. zr=4 gives
// 64B-aligned z rows: each random 48B row read touches exactly ONE cache
// line (48B @ 48B stride averaged ~1.75 lines).
__global__ __launch_bounds__(256) void gather_out5_kernel(
    const float2* __restrict__ slots, const int* __restrict__ cnt,
    const int* __restrict__ ohead, const int* __restrict__ onxt,
    const float* __restrict__ ovf_w, const int* __restrict__ ovf_s,
    const float* __restrict__ z, const float* __restrict__ dis,
    const float* __restrict__ bc, const float* __restrict__ Wo,
    const float* __restrict__ bo, float* __restrict__ out, int zr)
{
    __shared__ float sbc[12], sWo[12], sbo;
    if (threadIdx.x < 12) {
        sbc[threadIdx.x] = (threadIdx.x < HG) ? bc[threadIdx.x] : 0.f;
        sWo[threadIdx.x] = (threadIdx.x < HG) ? Wo[threadIdx.x] : 0.f;
    }
    if (threadIdx.x == 0) sbo = bo[0];
    __syncthreads();

    int tg = blockIdx.x * 256 + threadIdx.x;
    int n = tg >> 3;
    int k = tg & 7;
    if (n >= NN) return;

    const float4* Z = (const float4*)z;
    float4 A0 = make_float4(0.f, 0.f, 0.f, 0.f), A1 = A0, A2 = A0;

    int c = cnt[n];
    int cc = c < MAXK ? c : MAXK;
    for (int j = k; j < cc; j += 8) {
        float2 p = slots[(size_t)n * MAXK + j];
        float w = p.x;
        int s = __float_as_int(p.y);
        size_t row = (size_t)s * zr;
        float4 z0 = Z[row], z1 = Z[row + 1], z2 = Z[row + 2];
        A0.x = fmaf(w, z0.x, A0.x); A0.y = fmaf(w, z0.y, A0.y);
        A0.z = fmaf(w, z0.z, A0.z); A0.w = fmaf(w, z0.w, A0.w);
        A1.x = fmaf(w, z1.x, A1.x); A1.y = fmaf(w, z1.y, A1.y);
        A1.z = fmaf(w, z1.z, A1.z); A1.w = fmaf(w, z1.w, A1.w);
        A2.x = fmaf(w, z2.x, A2.x); A2.y = fmaf(w, z2.y, A2.y);
    }
    if (k == 0) {
        for (int i = ohead[n]; i >= 0; i = onxt[i]) {
            float w = ovf_w[i];
            int s = ovf_s[i];
            size_t row = (size_t)s * zr;
            float4 z0 = Z[row], z1 = Z[row + 1], z2 = Z[row + 2];
            A0.x = fmaf(w, z0.x, A0.x); A0.y = fmaf(w, z0.y, A0.y);
            A0.z = fmaf(w, z0.z, A0.z); A0.w = fmaf(w, z0.w, A0.w);
            A1.x = fmaf(w, z1.x, A1.x); A1.y = fmaf(w, z1.y, A1.y);
            A1.z = fmaf(w, z1.z, A1.z); A1.w = fmaf(w, z1.w, A1.w);
            A2.x = fmaf(w, z2.x, A2.x); A2.y = fmaf(w, z2.y, A2.y);
        }
        // self loop: + z[n] (w=1)
        size_t row = (size_t)n * zr;
        float4 s0 = Z[row], s1 = Z[row + 1], s2 = Z[row + 2];
        A0.x += s0.x; A0.y += s0.y; A0.z += s0.z; A0.w += s0.w;
        A1.x += s1.x; A1.y += s1.y; A1.z += s1.z; A1.w += s1.w;
        A2.x += s2.x; A2.y += s2.y;
    }

    float v[10] = { A0.x, A0.y, A0.z, A0.w, A1.x, A1.y, A1.z, A1.w, A2.x, A2.y };
    #pragma unroll
    for (int q = 0; q < 10; q++) {
        v[q] += __shfl_xor(v[q], 1);
        v[q] += __shfl_xor(v[q], 2);
        v[q] += __shfl_xor(v[q], 4);
    }

    if (k == 0) {
        float d = dis[n];
        float o = sbo;
        #pragma unroll
        for (int q = 0; q < HG; q++)
            o = fmaf(fmaf(v[q], d, sbc[q]), sWo[q], o);
        out[n] = 1.f / (1.f + __expf(-o));
    }
}

// ================= Fallback path (Round-1 scatter) =================
__global__ __launch_bounds__(256) void edge_mlp_kernel(
    const float* __restrict__ x, const float* __restrict__ token,
    const float* __restrict__ eg, const float* __restrict__ ee,
    const float* __restrict__ gum, const int* __restrict__ eidx,
    const float* __restrict__ W0, const float* __restrict__ b0,
    const float* __restrict__ W1, const float* __restrict__ b1,
    const float* __restrict__ W2, const float* __restrict__ b2,
    const float* __restrict__ W3, const float* __restrict__ b3,
    const float* __restrict__ Wl, const float* __restrict__ bl,
    float* __restrict__ ew_out, float* __restrict__ deg)
{
    __shared__ float sW0[13 * HM];
    __shared__ float sW1[HM * HM];
    __shared__ float sW2[HM * HM];
    __shared__ float sW3f[HM * 2];
    __shared__ float sb0[HM], sb1[HM], sb2[HM], sb3[2];
    __shared__ float sWl, sbl;

    for (int i = threadIdx.x; i < 13 * HM; i += 256) sW0[i] = W0[i];
    for (int i = threadIdx.x; i < HM * HM; i += 256) sW1[i] = W1[i];
    for (int i = threadIdx.x; i < HM * HM; i += 256) sW2[i] = W2[i];
    for (int i = threadIdx.x; i < HM * 2; i += 256) sW3f[i] = W3[i];
    if (threadIdx.x < HM) {
        sb0[threadIdx.x] = b0[threadIdx.x];
        sb1[threadIdx.x] = b1[threadIdx.x];
        sb2[threadIdx.x] = b2[threadIdx.x];
    }
    if (threadIdx.x < 2) sb3[threadIdx.x] = b3[threadIdx.x];
    if (threadIdx.x == 0) { sWl = Wl[0]; sbl = bl[0]; }
    __syncthreads();

    int e = blockIdx.x * 256 + threadIdx.x;
    if (e >= NE) return;
    int s = eidx[e];
    int t = eidx[NE + e];

    float ef[13];
    ef[0] = x[s];
    #pragma unroll
    for (int i = 0; i < 5; i++) ef[1 + i] = token[s * 5 + i];
    ef[6] = x[t];
    #pragma unroll
    for (int i = 0; i < 5; i++) ef[7 + i] = token[t * 5 + i];
    ef[12] = eg[e];

    float h[HM], h2[HM];
    #pragma unroll
    for (int j = 0; j < HM; j++) {
        float a = sb0[j];
        #pragma unroll
        for (int i = 0; i < 13; i++) a = fmaf(ef[i], sW0[i * HM + j], a);
        h[j] = a > 0.f ? a : 0.f;
    }
    #pragma unroll
    for (int j = 0; j < HM; j++) {
        float a = sb1[j];
        #pragma unroll
        for (int i = 0; i < HM; i++) a = fmaf(h[i], sW1[i * HM + j], a);
        h2[j] = a > 0.f ? a : 0.f;
    }
    #pragma unroll
    for (int j = 0; j < HM; j++) {
        float a = sb2[j];
        #pragma unroll
        for (int i = 0; i < HM; i++) a = fmaf(h2[i], sW2[i * HM + j], a);
        h[j] = a > 0.f ? a : 0.f;
    }
    float l0 = sb3[0], l1 = sb3[1];
    #pragma unroll
    for (int i = 0; i < HM; i++) {
        l0 = fmaf(h[i], sW3f[i * 2 + 0], l0);
        l1 = fmaf(h[i], sW3f[i * 2 + 1], l1);
    }
    const float2 g2 = ((const float2*)gum)[e];
    float v0 = l0 + g2.x, v1 = l1 + g2.y;
    float ew = 0.f;
    if (!(v1 > v0)) {
        const float2 ee2 = ((const float2*)ee)[e];
        float z = fmaf(ee2.x, sWl, sbl);
        ew = ee2.y / (1.f + __expf(-z));
    }
    ew_out[e] = ew;
    if (ew != 0.f) atomicAdd(&deg[t], ew);
}

__global__ __launch_bounds__(256) void node_pre_kernel(
    const float* __restrict__ x, const float* __restrict__ token,
    const float* __restrict__ Wc, const float* __restrict__ deg,
    float* __restrict__ xw, float* __restrict__ dis)
{
    __shared__ float sWc[6 * HG];
    if (threadIdx.x < 6 * HG) sWc[threadIdx.x] = Wc[threadIdx.x];
    __syncthreads();
    int n = blockIdx.x * 256 + threadIdx.x;
    if (n >= NN) return;
    float xa[6];
    xa[0] = x[n];
    #pragma unroll
    for (int i = 0; i < 5; i++) xa[1 + i] = token[n * 5 + i];
    #pragma unroll
    for (int k = 0; k < HG; k++) {
        float a = 0.f;
        #pragma unroll
        for (int i = 0; i < 6; i++) a = fmaf(xa[i], sWc[i * HG + k], a);
        xw[n * HG + k] = a;
    }
    dis[n] = rsqrtf(deg[n] + 1.0f);
}

__global__ __launch_bounds__(256) void edge_scatter_kernel(
    const int* __restrict__ eidx, const float* __restrict__ ew,
    const float* __restrict__ dis, const float* __restrict__ xw,
    float* __restrict__ agg)
{
    int e = blockIdx.x * 256 + threadIdx.x;
    if (e >= NE) return;
    float w = ew[e];
    if (w == 0.f) return;
    int s = eidx[e];
    int t = eidx[NE + e];
    float norm = dis[s] * w * dis[t];
    #pragma unroll
    for (int k = 0; k < HG; k++)
        atomicAdd(&agg[t * HG + k], norm * xw[s * HG + k]);
}

__global__ __launch_bounds__(256) void node_out_kernel(
    const float* __restrict__ agg, const float* __restrict__ xw,
    const float* __restrict__ dis, const float* __restrict__ bc,
    const float* __restrict__ Wo, const float* __restrict__ bo,
    float* __restrict__ out)
{
    __shared__ float sbc[HG], sWo[HG], sbo;
    if (threadIdx.x < HG) { sbc[threadIdx.x] = bc[threadIdx.x]; sWo[threadIdx.x] = Wo[threadIdx.x]; }
    if (threadIdx.x == 0) sbo = bo[0];
    __syncthreads();
    int n = blockIdx.x * 256 + threadIdx.x;
    if (n >= NN) return;
    float d = dis[n];
    float self = d * d;
    float acc = sbo;
    #pragma unroll
    for (int k = 0; k < HG; k++) {
        float v = agg[n * HG + k] + xw[n * HG + k] * self + sbc[k];
        acc = fmaf(v, sWo[k], acc);
    }
    out[n] = 1.f / (1.f + __expf(-acc));
}

extern "C" void kernel_launch(void* const* d_in, const int* in_sizes, int n_in,
                              void* d_out, int out_size, void* d_ws, size_t ws_size,
                              hipStream_t stream) {
    const float* x   = (const float*)d_in[0];
    const float* tok = (const float*)d_in[1];
    const float* eg  = (const float*)d_in[2];
    const float* ee  = (const float*)d_in[3];
    const float* gum = (const float*)d_in[4];
    const int*   ei  = (const int*)d_in[5];
    const float* W0  = (const float*)d_in[6];
    const float* b0  = (const float*)d_in[7];
    const float* W1  = (const float*)d_in[8];
    const float* b1  = (const float*)d_in[9];
    const float* W2  = (const float*)d_in[10];
    const float* b2  = (const float*)d_in[11];
    const float* W3  = (const float*)d_in[12];
    const float* b3  = (const float*)d_in[13];
    const float* Wl  = (const float*)d_in[14];
    const float* bl  = (const float*)d_in[15];
    const float* Wc  = (const float*)d_in[16];
    const float* bc  = (const float*)d_in[17];
    const float* Wo  = (const float*)d_in[18];
    const float* bo  = (const float*)d_in[19];
    float* out = (float*)d_out;

    dim3 blk(256);
    dim3 egrid(NE / 256);               // exact: 12500
    dim3 ngrid((NN + 255) / 256);
    dim3 n4grid((NN * 4 + 255) / 256);  // 4 lanes per node (node_deg)
    dim3 g8grid((NN * 8 + 255) / 256);  // 8 lanes per node (gather)

    // ws layout (float offsets), parameterized by z row size zs (16 or 12)
    auto compute_need = [&](size_t zs, size_t* offs) {
        size_t off_xall8 = 0;                               // NN*8
        size_t off_xwp   = off_xall8 + (size_t)NN * 8;      // NN*zs
        size_t off_slots = off_xwp + (size_t)NN * zs;       // NN*MAXK*2
        size_t off_cnt   = off_slots + (size_t)NN * MAXK * 2;
        size_t off_novf  = off_cnt + NN;
        size_t off_dis   = off_novf + 1;
        size_t off_ohead = off_dis + NN;
        size_t off_ovfw  = off_ohead + NN;
        size_t off_ovfs  = off_ovfw + OVF_CAP;
        size_t off_onxt  = off_ovfs + OVF_CAP;
        size_t off_w0t   = (off_onxt + OVF_CAP + 15) & ~(size_t)15;
        size_t off_w1t   = off_w0t + 30 * 16;
        size_t off_w2t   = off_w1t + 30 * 32;
        offs[0] = off_xall8; offs[1] = off_xwp; offs[2] = off_slots;
        offs[3] = off_cnt;   offs[4] = off_novf; offs[5] = off_dis;
        offs[6] = off_ohead; offs[7] = off_ovfw; offs[8] = off_ovfs;
        offs[9] = off_onxt;  offs[10] = off_w0t; offs[11] = off_w1t;
        offs[12] = off_w2t;
        return (off_w2t + 30 * 32) * sizeof(float);
    };

    size_t offs[13];
    size_t zs = 16;
    size_t need = compute_need(zs, offs);
    if (ws_size < need) { zs = 12; need = compute_need(zs, offs); }

    if (ws_size >= need) {
        int zr = (int)(zs / 4);           // float4s per z row: 4 or 3
        float*  ws    = (float*)d_ws;
        float*  xall8 = ws + offs[0];
        float*  xwp   = ws + offs[1];
        float2* slots = (float2*)(ws + offs[2]);
        int*    cnt   = (int*)(ws + offs[3]);
        int*    novf  = (int*)(ws + offs[4]);
        float*  dis   = ws + offs[5];
        int*    ohead = (int*)(ws + offs[6]);
        float*  ovf_w = ws + offs[7];
        int*    ovf_s = (int*)(ws + offs[8]);
        int*    onxt  = (int*)(ws + offs[9]);
        float*  W0T   = ws + offs[10];
        float*  W1T   = ws + offs[11];
        float*  W2T   = ws + offs[12];

        hipMemsetAsync(cnt, 0, (size_t)(NN + 1) * sizeof(int), stream);   // cnt + novf
        hipMemsetAsync(ohead, 0xFF, (size_t)NN * sizeof(int), stream);    // ohead = -1

        wtrans_kernel<<<dim3(1), blk, 0, stream>>>(W0, W1, W2, W0T, W1T, W2T);
        pack_kernel<<<ngrid, blk, 0, stream>>>(x, tok, Wc, xall8, xwp, zr);
        edge_mlp7_kernel<<<egrid, blk, 0, stream>>>(xall8, eg, ee, gum, ei,
                                                    W0T, b0, W1T, b1, W2T, b2,
                                                    W3, b3, Wl, bl, slots, cnt,
                                                    ohead, onxt, ovf_w, ovf_s, novf);
        node_deg4_kernel<<<n4grid, blk, 0, stream>>>(slots, cnt, ohead, onxt,
                                                     ovf_w, xwp, dis, zr);
        gather_out5_kernel<<<g8grid, blk, 0, stream>>>(slots, cnt, ohead, onxt,
                                                       ovf_w, ovf_s, xwp, dis,
                                                       bc, Wo, bo, out, zr);
    } else {
        // Fallback: Round-1 scatter layout: [ew: NE][deg: NN][agg: NN*HG][xw: NN*HG][dis: NN]
        float* ws  = (float*)d_ws;
        float* ew  = ws;
        float* deg = ew + NE;
        float* agg = deg + NN;
        float* xw  = agg + (size_t)NN * HG;
        float* dis = xw + (size_t)NN * HG;

        hipMemsetAsync(deg, 0, (size_t)(NN + (size_t)NN * HG) * sizeof(float), stream);
        edge_mlp_kernel<<<egrid, blk, 0, stream>>>(x, tok, eg, ee, gum, ei,
                                                   W0, b0, W1, b1, W2, b2, W3, b3,
                                                   Wl, bl, ew, deg);
        node_pre_kernel<<<ngrid, blk, 0, stream>>>(x, tok, Wc, deg, xw, dis);
        edge_scatter_kernel<<<egrid, blk, 0, stream>>>(ei, ew, dis, xw, agg);
        node_out_kernel<<<ngrid, blk, 0, stream>>>(agg, xw, dis, bc, Wo, bo, out);
    }
}